// Round 10
// baseline (1334.177 us; speedup 1.0000x reference)
//
#include <hip/hip_runtime.h>

typedef unsigned short u16;
typedef unsigned int   u32;
typedef __attribute__((ext_vector_type(4))) float f32x4;
typedef __attribute__((ext_vector_type(2))) float f32x2;
typedef __attribute__((ext_vector_type(8))) short bf16x8;

#define B_   4
#define T_   2048
#define HID_ 2048
#define H_   16
#define MT_  (B_*T_)
#define CT_  32
#define NC_  (T_/CT_)

static constexpr float SCALE_ = 0.08838834764831845f; // DK^-0.5
static constexpr float EPS_   = 1e-5f;

__device__ __forceinline__ float sigmoidf_(float x) { return 1.0f / (1.0f + __expf(-x)); }

__device__ __forceinline__ u16 f2bf(float f) {
  union { float f; u32 u; } c; c.f = f;
  u32 r = c.u + 0x7FFFu + ((c.u >> 16) & 1u);
  return (u16)(r >> 16);
}
__device__ __forceinline__ u32 pack2(float a, float b) {
  return (u32)f2bf(a) | ((u32)f2bf(b) << 16);
}
__device__ __forceinline__ float bf2f(u16 h) {
  union { u32 u; float f; } c; c.u = (u32)h << 16; return c.f;
}
__device__ __forceinline__ float u2f_(u32 u) {
  union { u32 u; float f; } c; c.u = u; return c.f;
}
__device__ __forceinline__ void gload16(const u16* g, u16* l) {
  __builtin_amdgcn_global_load_lds((__attribute__((address_space(1))) void*)g,
                                   (__attribute__((address_space(3))) void*)l, 16, 0, 0);
}

// DPP butterfly add within 16-lane rows (levels xor1/2/4/8).
template <int CTRL>
__device__ __forceinline__ float dpp_add(float x) {
  int y = __builtin_amdgcn_update_dpp(0, __builtin_bit_cast(int, x), CTRL, 0xF, 0xF, true);
  return x + __builtin_bit_cast(float, y);
}
__device__ __forceinline__ void red16x2(float& d0, float& d1) {
  d0 = dpp_add<0xB1>(d0);  d1 = dpp_add<0xB1>(d1);   // quad_perm {1,0,3,2} : xor1
  d0 = dpp_add<0x4E>(d0);  d1 = dpp_add<0x4E>(d1);   // quad_perm {2,3,0,1} : xor2
  d0 = dpp_add<0x141>(d0); d1 = dpp_add<0x141>(d1);  // row_half_mirror     : ~xor4
  d0 = dpp_add<0x140>(d0); d1 = dpp_add<0x140>(d1);  // row_mirror          : ~xor8
}

// ---------------- x (f32) -> bf16, elementwise ----------------
__global__ __launch_bounds__(256) void convert_bf16_kernel(const float* __restrict__ in,
                                                           u16* __restrict__ out, int n8) {
  int i = blockIdx.x * 256 + threadIdx.x;
  if (i >= n8) return;
  const f32x4* p = (const f32x4*)in + (size_t)i * 2;
  f32x4 v0 = p[0], v1 = p[1];
  uint4 o;
  o.x = pack2(v0[0], v0[1]);
  o.y = pack2(v0[2], v0[3]);
  o.z = pack2(v1[0], v1[1]);
  o.w = pack2(v1[2], v1[3]);
  *(uint4*)(out + (size_t)i * 8) = o;
}

// ---------------- W [K][N] f32 -> WT [N][K] bf16 (tiled transpose, z<=2) ----------------
struct TransArgs { const float* W[2]; u16* WT[2]; };

__global__ __launch_bounds__(256) void transpose_convert_kernel(TransArgs args, int K, int N) {
  __shared__ float tile[64][65];
  const float* __restrict__ W = args.W[blockIdx.z];
  u16* __restrict__ WT = args.WT[blockIdx.z];
  const int t = threadIdx.x;
  const int bk = blockIdx.y * 64;
  const int bn = blockIdx.x * 64;
#pragma unroll
  for (int p = 0; p < 4; ++p) {
    int kl  = p * 16 + (t >> 4);
    int nl4 = (t & 15);
    f32x4 v = *(const f32x4*)(W + (size_t)(bk + kl) * N + bn + nl4 * 4);
    tile[nl4 * 4 + 0][kl] = v[0];
    tile[nl4 * 4 + 1][kl] = v[1];
    tile[nl4 * 4 + 2][kl] = v[2];
    tile[nl4 * 4 + 3][kl] = v[3];
  }
  __syncthreads();
  const int nl = t >> 2;
  const int ko = (t & 3) * 16;
  u32 w[8];
#pragma unroll
  for (int i = 0; i < 8; ++i)
    w[i] = pack2(tile[nl][ko + 2 * i], tile[nl][ko + 2 * i + 1]);
  uint4* dst = (uint4*)(WT + (size_t)(bn + nl) * K + bk + ko);
  dst[0] = make_uint4(w[0], w[1], w[2], w[3]);
  dst[1] = make_uint4(w[4], w[5], w[6], w[7]);
}

// ---- bf16 MFMA GEMM v3b: 256x256, 8 waves, 8-PHASE schedule (T2+T3+T4+T5) ----
// Race-fixed stage slots (round-9 post-mortem): a staged unit may only be written
// in a phase AFTER the last phase that reads it.
// buf0 free: A0,A2 after P1; A1,A3,B* after P3. buf1 free: A0,A2 after P5; A1,A3,B* after P7.
struct GemmArgs {
  const u16*   Bt[2];
  void*        C[2];
  const float* bias[2];
  int          mode[2];
};

// Phase = one C-quadrant (MH,NH) over K=64: 12 ds_read_b128 + staging + 16 MFMA.
#define PHASE(BF, MH, NH, STAGES, TAILW) do {                                              \
  bf16x8 a0_[4], a1_[4], b0_[2], b1_[2];                                                   \
  _Pragma("unroll") for (int i_ = 0; i_ < 4; ++i_) {                                       \
    a0_[i_] = *(const bf16x8*)(&Al[BF][(aRow + (MH)*64 + i_*16)*64 + off0]);               \
    a1_[i_] = *(const bf16x8*)(&Al[BF][(aRow + (MH)*64 + i_*16)*64 + off1]);               \
  }                                                                                        \
  _Pragma("unroll") for (int j_ = 0; j_ < 2; ++j_) {                                       \
    b0_[j_] = *(const bf16x8*)(&Bl[BF][(bRow + (NH)*32 + j_*16)*64 + off0]);               \
    b1_[j_] = *(const bf16x8*)(&Bl[BF][(bRow + (NH)*32 + j_*16)*64 + off1]);               \
  }                                                                                        \
  STAGES;                                                                                  \
  __builtin_amdgcn_s_barrier();                                                            \
  asm volatile("s_waitcnt lgkmcnt(0)" ::: "memory");                                       \
  __builtin_amdgcn_sched_barrier(0);                                                       \
  __builtin_amdgcn_s_setprio(1);                                                           \
  _Pragma("unroll") for (int i_ = 0; i_ < 4; ++i_)                                         \
    _Pragma("unroll") for (int j_ = 0; j_ < 2; ++j_)                                       \
      acc[(MH)*4+i_][(NH)*2+j_] = __builtin_amdgcn_mfma_f32_16x16x32_bf16(                 \
          a0_[i_], b0_[j_], acc[(MH)*4+i_][(NH)*2+j_], 0, 0, 0);                           \
  _Pragma("unroll") for (int i_ = 0; i_ < 4; ++i_)                                         \
    _Pragma("unroll") for (int j_ = 0; j_ < 2; ++j_)                                       \
      acc[(MH)*4+i_][(NH)*2+j_] = __builtin_amdgcn_mfma_f32_16x16x32_bf16(                 \
          a1_[i_], b1_[j_], acc[(MH)*4+i_][(NH)*2+j_], 0, 0, 0);                           \
  __builtin_amdgcn_s_setprio(0);                                                           \
  TAILW;                                                                                   \
  __builtin_amdgcn_s_barrier();                                                            \
} while (0)

__global__ __launch_bounds__(512, 2) void gemm_kernel(const u16* __restrict__ A, GemmArgs args,
                                                      int M, int N, int K) {
  __shared__ u16 Al[2][256 * 64];
  __shared__ u16 Bl[2][256 * 64];
  const int mat = blockIdx.z;
  const u16* __restrict__ Bt = args.Bt[mat];
  void* Cp = args.C[mat];
  const float* bias = args.bias[mat];
  const int mode = args.mode[mat];

  const int tid  = threadIdx.x;
  const int wave = tid >> 6;
  const int lane = tid & 63;
  const int tM = blockIdx.y << 8;
  const int tN = blockIdx.x << 8;
  const int wm = wave >> 2;            // 0..1 -> 128 rows each
  const int wn = wave & 3;             // 0..3 ->  64 cols each

  f32x4 acc[8][4] = {};

  // staging map: unit = 64 rows of one operand (1 gload/thread). Linear LDS dest
  // (dest byte = unit*8192 + tid*16); global source col inverse-swizzled.
  const int srow  = tid >> 3;                       // 0..63
  const int cPhys = (tid & 7) << 3;                 // u16
  const int cSrc  = cPhys ^ ((srow & 7) << 3);      // u16
  const u16* Agb = A  + (size_t)(tM + srow) * K + cSrc;
  const u16* Bgb = Bt + (size_t)(tN + srow) * K + cSrc;

  auto stA = [&](int bf, int u, int kt) {
    gload16(Agb + ((size_t)u * 64) * K + (kt << 6), &Al[bf][(u * 64 + srow) * 64 + cPhys]);
  };
  auto stB = [&](int bf, int u, int kt) {
    gload16(Bgb + ((size_t)u * 64) * K + (kt << 6), &Bl[bf][(u * 64 + srow) * 64 + cPhys]);
  };

  // fragment-read map (swizzled)
  const int lr   = lane & 15;
  const int lk   = lane >> 4;
  const int aRow = wm * 128 + lr;
  const int bRow = wn * 64 + lr;
  const int sw   = (lane & 7) << 3;
  const int off0 = (lk << 3) ^ sw;
  const int off1 = (32 + (lk << 3)) ^ sw;

  const int NTt = K >> 6;                           // 32 K-tiles (even)

  // prologue: tile0 -> buf0 (8 units), tile1 prefix A0,A2 -> buf1
  // (A0/A2 are the only buf1 units not read until P4/P5 — safe from birth)
  stA(0, 0, 0); stA(0, 1, 0); stA(0, 2, 0); stA(0, 3, 0);
  stB(0, 0, 0); stB(0, 1, 0); stB(0, 2, 0); stB(0, 3, 0);
  stA(1, 0, 1); stA(1, 2, 1);
  asm volatile("s_waitcnt vmcnt(2)" ::: "memory");
  __builtin_amdgcn_s_barrier();

  for (int it = 0; it < NTt / 2; ++it) {
    const int t1 = 2 * it + 1, t2 = 2 * it + 2, t3 = 2 * it + 3;
    const bool h2 = t2 < NTt, h3 = t3 < NTt;      // NTt even: h2 == h3
    // P0..P3: tile 2*it in buf0;  P4..P7: tile t1 in buf1
    // buf1 units A1,A3,B* were last read in PREVIOUS iteration's P6/P7 -> safe at P0/P1.
    PHASE(0, 0, 0, { stA(1, 1, t1); stA(1, 3, t1); stB(1, 0, t1); stB(1, 1, t1); }, {});
    PHASE(0, 0, 1, { stB(1, 2, t1); stB(1, 3, t1); }, {});
    PHASE(0, 1, 0, { if (h2) { stA(0, 0, t2); } }, {});          // buf0 A0 freed after P1
    PHASE(0, 1, 1, { if (h2) { stA(0, 2, t2); } }, {
      // gate: t1 fully landed before P4 reads buf1 (2 issues after t1's last load)
      if (h2) asm volatile("s_waitcnt vmcnt(2)" ::: "memory");
      else    asm volatile("s_waitcnt vmcnt(0)" ::: "memory");
    });
    PHASE(1, 0, 0, { if (h2) { stA(0, 1, t2); stA(0, 3, t2); } }, {});  // freed after P3
    PHASE(1, 0, 1, { if (h2) { stB(0, 0, t2); stB(0, 1, t2); } }, {});
    PHASE(1, 1, 0, { if (h2) { stB(0, 2, t2); stB(0, 3, t2); }
                     if (h3) { stA(1, 0, t3); } }, {});          // buf1 A0 freed after P5
    PHASE(1, 1, 1, { if (h3) { stA(1, 2, t3); } }, {             // buf1 A2 freed after P5
      // gate: t2 fully landed before next P0 reads buf0 (2 issues after t2's last load)
      if (h3) asm volatile("s_waitcnt vmcnt(2)" ::: "memory");
      else    asm volatile("s_waitcnt vmcnt(0)" ::: "memory");
    });
  }

  const int r0 = lk << 2;
  const int c0 = lr;
  if (mode == 2) {
    float* Cf = (float*)Cp;
#pragma unroll
    for (int i = 0; i < 8; ++i) {
      const int gm0 = tM + wm * 128 + (i << 4) + r0;
#pragma unroll
      for (int j2 = 0; j2 < 4; ++j2) {
        const int gn = tN + wn * 64 + (j2 << 4) + c0;
#pragma unroll
        for (int rr = 0; rr < 4; ++rr)
          Cf[(size_t)(gm0 + rr) * N + gn] = acc[i][j2][rr];
      }
    }
  } else {
    u16* Cb = (u16*)Cp;
#pragma unroll
    for (int i = 0; i < 8; ++i) {
      const int gm0 = tM + wm * 128 + (i << 4) + r0;
#pragma unroll
      for (int j2 = 0; j2 < 4; ++j2) {
        const int gn = tN + wn * 64 + (j2 << 4) + c0;
        const float bsv = (bias != nullptr) ? bias[gn] : 0.f;
#pragma unroll
        for (int rr = 0; rr < 4; ++rr) {
          float val = acc[i][j2][rr];
          if (mode == 1) val = sigmoidf_(val + bsv);
          Cb[(size_t)(gm0 + rr) * N + gn] = f2bf(val);
        }
      }
    }
  }
}

// ---------------- beta = sigmoid(x @ Wb + bb) : [MT, 16] ----------------
__global__ __launch_bounds__(256) void beta_kernel(const float* __restrict__ x,
                                                   const float* __restrict__ Wb,
                                                   const float* __restrict__ bb,
                                                   float* __restrict__ beta) {
  __shared__ float red[4][64];
  const int tid  = threadIdx.x;
  const int wave = tid >> 6;
  const int lane = tid & 63;
  const size_t row0 = (size_t)blockIdx.x * 4;

  float p[4][16];
#pragma unroll
  for (int r = 0; r < 4; ++r)
#pragma unroll
    for (int h2 = 0; h2 < 16; ++h2) p[r][h2] = 0.f;

  const int e0 = tid * 8;
  f32x4 xa[4][2];
#pragma unroll
  for (int r = 0; r < 4; ++r) {
    xa[r][0] = *(const f32x4*)(x + (row0 + r) * HID_ + e0);
    xa[r][1] = *(const f32x4*)(x + (row0 + r) * HID_ + e0 + 4);
  }
#pragma unroll
  for (int ee = 0; ee < 8; ++ee) {
    const float* wrow = Wb + (size_t)(e0 + ee) * 16;
    f32x4 wv[4];
    wv[0] = *(const f32x4*)(wrow);
    wv[1] = *(const f32x4*)(wrow + 4);
    wv[2] = *(const f32x4*)(wrow + 8);
    wv[3] = *(const f32x4*)(wrow + 12);
#pragma unroll
    for (int r = 0; r < 4; ++r) {
      float xv = xa[r][ee >> 2][ee & 3];
#pragma unroll
      for (int c4 = 0; c4 < 4; ++c4) {
#pragma unroll
        for (int cc = 0; cc < 4; ++cc)
          p[r][c4 * 4 + cc] = fmaf(xv, wv[c4][cc], p[r][c4 * 4 + cc]);
      }
    }
  }
#pragma unroll
  for (int m = 1; m < 64; m <<= 1)
#pragma unroll
    for (int r = 0; r < 4; ++r)
#pragma unroll
      for (int h2 = 0; h2 < 16; ++h2)
        p[r][h2] += __shfl_xor(p[r][h2], m, 64);

  if (lane == 0) {
#pragma unroll
    for (int r = 0; r < 4; ++r)
#pragma unroll
      for (int h2 = 0; h2 < 16; ++h2)
        red[wave][r * 16 + h2] = p[r][h2];
  }
  __syncthreads();
  if (tid < 64) {
    float sres = red[0][tid] + red[1][tid] + red[2][tid] + red[3][tid];
    int r = tid >> 4, h2 = tid & 15;
    beta[(row0 + r) * H_ + h2] = sigmoidf_(sres + bb[h2]);
  }
}

// ---------------- causal depthwise conv (K=4) + silu (+scale), bf16 in/out ----------------
__global__ __launch_bounds__(256) void conv_silu_kernel(const u16* __restrict__ src,
                                                        u16* __restrict__ dst,
                                                        const float* __restrict__ w,
                                                        const float* __restrict__ bias,
                                                        float scale) {
  const int gid = blockIdx.x * 256 + threadIdx.x;   // one group of 8 channels
  const int g8  = gid & 255;                        // 2048/8
  const int row = gid >> 8;                         // b*T + t
  const int t   = row & (T_ - 1);
  const int c   = g8 * 8;

  float acc[8];
  f32x4 b0 = *(const f32x4*)(bias + c);
  f32x4 b1 = *(const f32x4*)(bias + c + 4);
#pragma unroll
  for (int i = 0; i < 4; ++i) { acc[i] = b0[i]; acc[i + 4] = b1[i]; }
  f32x4 wv[8];
#pragma unroll
  for (int i = 0; i < 8; ++i) wv[i] = *(const f32x4*)(w + (size_t)(c + i) * 4);

#pragma unroll
  for (int j = 0; j < 4; ++j) {
    int tt = t - 3 + j;
    if (tt >= 0) {
      uint4 uv = *(const uint4*)(src + (size_t)(row - 3 + j) * HID_ + c);
      const u32 uw[4] = {uv.x, uv.y, uv.z, uv.w};
#pragma unroll
      for (int i = 0; i < 8; ++i) {
        float xval = bf2f((u16)(uw[i >> 1] >> ((i & 1) * 16)));
        acc[i] = fmaf(wv[i][j], xval, acc[i]);
      }
    }
  }
  u32 out[4];
#pragma unroll
  for (int i = 0; i < 4; ++i) {
    float y0 = acc[2 * i]     * sigmoidf_(acc[2 * i])     * scale;
    float y1 = acc[2 * i + 1] * sigmoidf_(acc[2 * i + 1]) * scale;
    out[i] = pack2(y0, y1);
  }
  *(uint4*)(dst + (size_t)row * HID_ + c) = make_uint4(out[0], out[1], out[2], out[3]);
}

// ---------------- gated delta-rule scan v3 (best measured: 616us) ----------
__global__ __launch_bounds__(256) void scan_kernel(const u16* __restrict__ q,
                                                   const u16* __restrict__ k,
                                                   u16* __restrict__ vo,
                                                   const u16* __restrict__ a,
                                                   const float* __restrict__ beta) {
  __shared__ u16 Kb[2][CT_ * 128];
  __shared__ u16 Qb[2][CT_ * 128];
  __shared__ u16 Vb[2][CT_ * 16];
  __shared__ u16 Ab[2][CT_ * 16];
  __shared__ float Bb[2][CT_];

  const int bid = blockIdx.x;
  const int vb  = bid & 7;
  const int bh  = bid >> 3;
  const int h   = bh & (H_ - 1);
  const int b   = bh >> 4;
  const int tid = threadIdx.x;
  const int wave = tid >> 6;
  const int lane = tid & 63;
  const int r   = tid >> 4;
  const int j   = tid & 15;
  const int vg0 = vb * 16;
  const int vg  = vg0 + r;

  const size_t rs = HID_;
  const size_t base = ((size_t)b * T_) * rs + h * 128;
  const size_t bbase = (size_t)b * T_ * H_ + h;

  const int stt  = wave * 4 + (lane >> 4);
  const int scol = (lane & 15) * 8;
  const int vtt  = lane >> 1;
  const int vhf  = (lane & 1) * 8;

  auto stage = [&](int buf, int tc) {
#pragma unroll
    for (int p = 0; p < 2; ++p) {
      const int tt = p * 16 + stt;
      gload16(k + base + (size_t)(tc + tt) * rs + scol, &Kb[buf][tt * 128 + scol]);
      gload16(q + base + (size_t)(tc + tt) * rs + scol, &Qb[buf][tt * 128 + scol]);
    }
    if (wave == 0) {
      gload16(vo + base + (size_t)(tc + vtt) * rs + vg0 + vhf, &Vb[buf][vtt * 16 + vhf]);
    } else if (wave == 1) {
      gload16(a + base + (size_t)(tc + vtt) * rs + vg0 + vhf, &Ab[buf][vtt * 16 + vhf]);
    }
    if (tid < CT_) Bb[buf][tid] = beta[(bbase) + (size_t)(tc + tid) * H_];
  };

  auto cvt8 = [](uint4 raw, float* d) {
    const u32 uw[4] = {raw.x, raw.y, raw.z, raw.w};
#pragma unroll
    for (int i = 0; i < 4; ++i) {
      d[2 * i]     = u2f_(uw[i] << 16);
      d[2 * i + 1] = u2f_(uw[i] & 0xffff0000u);
    }
  };

  float s[8] = {0, 0, 0, 0, 0, 0, 0, 0};
  float ka[8], kb_[8];
  float pS = 0.f;
  u16* op = vo + base + vg;
  int buf = 0;

  stage(0, 0);
  __syncthreads();
  cvt8(*(const uint4*)&Kb[0][j * 8], ka);   // k_0

  for (int c = 0; c < NC_; ++c) {
    const int tc = c * CT_;
    if (c + 1 < NC_) stage(buf ^ 1, tc + CT_);
    uint4 kgn = make_uint4(0, 0, 0, 0);
    if (c + 1 < NC_) kgn = *(const uint4*)(k + base + (size_t)(tc + CT_) * rs + j * 8);

    auto step = [&](int tt, float (&kc)[8], float (&kn)[8]) {
      if (tt + 1 < CT_) cvt8(*(const uint4*)&Kb[buf][(tt + 1) * 128 + j * 8], kn);
      else              cvt8(kgn, kn);
      float qc[8];
      cvt8(*(const uint4*)&Qb[buf][tt * 128 + j * 8], qc);
      const float av = bf2f(Ab[buf][tt * 16 + r]);
      const float vv = bf2f(Vb[buf][tt * 16 + r]);
      const float bt = Bb[buf][tt];

      const float uu = bt * (vv - pS);
#pragma unroll
      for (int i = 0; i < 8; ++i) s[i] = fmaf(av, s[i], uu * kc[i]);

      float d0a = 0.f, d0b = 0.f, d1a = 0.f, d1b = 0.f;
#pragma unroll
      for (int i = 0; i < 4; ++i) {
        d0a = fmaf(s[i],     qc[i],     d0a);
        d0b = fmaf(s[i + 4], qc[i + 4], d0b);
        d1a = fmaf(s[i],     kn[i],     d1a);
        d1b = fmaf(s[i + 4], kn[i + 4], d1b);
      }
      float d0 = d0a + d0b, d1 = d1a + d1b;
      red16x2(d0, d1);
      if (j == 0) *op = f2bf(d0);
      op += rs;
      pS = d1;
    };

    for (int tt = 0; tt < CT_; tt += 2) {
      step(tt,     ka,  kb_);
      step(tt + 1, kb_, ka);
    }
    __syncthreads();
    buf ^= 1;
  }
}

// ---------------- LayerNorm(DV) * gate -> bf16 ----------------
__global__ __launch_bounds__(256) void ln_gate_kernel(const u16* __restrict__ o,
                                                      const u16* __restrict__ g,
                                                      const float* __restrict__ lnw,
                                                      const float* __restrict__ lnb,
                                                      u16* __restrict__ out) {
  const int wid  = blockIdx.x * 4 + (threadIdx.x >> 6);  // row in [0, MT*H)
  const int lane = threadIdx.x & 63;
  const size_t off = (size_t)wid * 128 + lane * 2;
  u32 oraw = *(const u32*)(o + off);
  float x0 = bf2f((u16)(oraw & 0xffff));
  float x1 = bf2f((u16)(oraw >> 16));
  float sum = x0 + x1;
  float sq  = x0 * x0 + x1 * x1;
#pragma unroll
  for (int m = 1; m < 64; m <<= 1) {
    sum += __shfl_xor(sum, m);
    sq  += __shfl_xor(sq, m);
  }
  float mu  = sum * (1.f / 128.f);
  float var = sq * (1.f / 128.f) - mu * mu;
  float rstd = rsqrtf(var + EPS_);
  int d = lane * 2;
  u32 graw = *(const u32*)(g + off);
  float g0 = bf2f((u16)(graw & 0xffff));
  float g1 = bf2f((u16)(graw >> 16));
  float y0 = ((x0 - mu) * rstd * lnw[d]     + lnb[d])     * g0;
  float y1 = ((x1 - mu) * rstd * lnw[d + 1] + lnb[d + 1]) * g1;
  *(u32*)(out + off) = pack2(y0, y1);
}

// ---------------- host ----------------
extern "C" void kernel_launch(void* const* d_in, const int* in_sizes, int n_in,
                              void* d_out, int out_size, void* d_ws, size_t ws_size,
                              hipStream_t stream) {
  const float* x   = (const float*)d_in[0];
  const float* Wq  = (const float*)d_in[1];
  const float* Wk  = (const float*)d_in[2];
  const float* Wv  = (const float*)d_in[3];
  const float* Wa  = (const float*)d_in[4];
  const float* ba  = (const float*)d_in[5];
  const float* Wb  = (const float*)d_in[6];
  const float* bb  = (const float*)d_in[7];
  const float* Wg  = (const float*)d_in[8];
  const float* Wo  = (const float*)d_in[9];
  const float* qcw = (const float*)d_in[10];
  const float* qcb = (const float*)d_in[11];
  const float* kcw = (const float*)d_in[12];
  const float* kcb = (const float*)d_in[13];
  const float* vcw = (const float*)d_in[14];
  const float* vcb = (const float*)d_in[15];
  const float* lnw = (const float*)d_in[16];
  const float* lnb = (const float*)d_in[17];

  char* ws = (char*)d_ws;
  size_t off = 0;
  auto alloc = [&](size_t bytes) -> char* {
    char* p = ws + off;
    off += (bytes + 255) & ~(size_t)255;
    return p;
  };

  const size_t wtb  = (size_t)HID_ * HID_ * 2;  // 8.39 MB
  const size_t actb = (size_t)MT_ * HID_ * 2;   // 33.55 MB
  u16* S0 = (u16*)alloc(wtb);
  u16* S1 = (u16*)alloc(wtb);
  u16* B1 = (u16*)alloc(actb);
  u16* B2 = (u16*)alloc(actb);
  u16* B3 = (u16*)alloc(actb);
  u16* B4 = (u16*)alloc(actb);
  u16* B5 = (u16*)alloc(actb);
  float* bet = (float*)alloc((size_t)MT_ * H_ * 4);
  // total = 185.1 MB — verified fitting (round 3+)

  if (off > ws_size) return;  // clean-fail guard

  dim3 blk(256);
  dim3 blk512(512);
  dim3 tgrid(32, 32, 2);
  dim3 ggrid(HID_ / 256, MT_ / 256, 2);
  dim3 ggrid1(HID_ / 256, MT_ / 256, 1);
  dim3 vgrid(MT_ * HID_ / 8 / 256);

  // 0. x -> bf16 into B5 (B5 free until conv-q)
  convert_bf16_kernel<<<vgrid, blk, 0, stream>>>(x, B5, MT_ * HID_ / 8);

  // 1. transpose Wq -> S0, Wk -> S1
  TransArgs t1; t1.W[0] = Wq; t1.WT[0] = S0; t1.W[1] = Wk; t1.WT[1] = S1;
  transpose_convert_kernel<<<tgrid, blk, 0, stream>>>(t1, HID_, HID_);

  // 2. GEMM (A = xb): qpre -> B1, kpre -> B2
  GemmArgs g1{};
  g1.Bt[0] = S0; g1.C[0] = B1; g1.bias[0] = nullptr; g1.mode[0] = 0;
  g1.Bt[1] = S1; g1.C[1] = B2; g1.bias[1] = nullptr; g1.mode[1] = 0;
  gemm_kernel<<<ggrid, blk512, 0, stream>>>(B5, g1, MT_, HID_, HID_);

  // 3. transpose Wv -> S0, Wa -> S1
  TransArgs t2; t2.W[0] = Wv; t2.WT[0] = S0; t2.W[1] = Wa; t2.WT[1] = S1;
  transpose_convert_kernel<<<tgrid, blk, 0, stream>>>(t2, HID_, HID_);

  // 4. GEMM (A = xb): vpre -> B3, a-gate (sigmoid+ba) -> B4
  GemmArgs g2{};
  g2.Bt[0] = S0; g2.C[0] = B3; g2.bias[0] = nullptr; g2.mode[0] = 0;
  g2.Bt[1] = S1; g2.C[1] = B4; g2.bias[1] = ba;      g2.mode[1] = 1;
  gemm_kernel<<<ggrid, blk512, 0, stream>>>(B5, g2, MT_, HID_, HID_);

  // 5. beta (reads f32 x directly)
  beta_kernel<<<dim3(MT_ / 4), blk, 0, stream>>>(x, Wb, bb, bet);

  // 6. convs (xb in B5 is dead now; rotation is stream-serialized)
  conv_silu_kernel<<<vgrid, blk, 0, stream>>>(B1, B5, qcw, qcb, 1.0f);    // qc -> B5
  conv_silu_kernel<<<vgrid, blk, 0, stream>>>(B2, B1, kcw, kcb, SCALE_);  // kc -> B1
  conv_silu_kernel<<<vgrid, blk, 0, stream>>>(B3, B2, vcw, vcb, 1.0f);    // vc -> B2

  // 7. scan v3 (256 threads/block): q=B5, k=B1, v/o in-place = B2, a=B4
  scan_kernel<<<dim3(B_ * H_ * 8), blk, 0, stream>>>(B5, B1, B2, B4, bet);

  // 8. transpose Wg -> S0, Wo -> S1
  TransArgs t3; t3.W[0] = Wg; t3.WT[0] = S0; t3.W[1] = Wo; t3.WT[1] = S1;
  transpose_convert_kernel<<<tgrid, blk, 0, stream>>>(t3, HID_, HID_);

  // 8.5. re-convert x -> bf16 into B1 (kc dead after scan)
  convert_bf16_kernel<<<vgrid, blk, 0, stream>>>(x, B1, MT_ * HID_ / 8);

  // 9. GEMM (A = xb2 in B1): g-gate (sigmoid) -> B3 (vpre dead)
  GemmArgs g3{};
  g3.Bt[0] = S0; g3.C[0] = B3; g3.bias[0] = nullptr; g3.mode[0] = 1;
  gemm_kernel<<<ggrid1, blk512, 0, stream>>>(B1, g3, MT_, HID_, HID_);

  // 10. LN * gate: o=B2, g=B3 -> ob=B5 (qc dead)
  ln_gate_kernel<<<dim3(MT_ * H_ / 4), blk, 0, stream>>>(B2, B3, lnw, lnb, B5);

  // 11. final GEMM (A = ob in B5): -> d_out f32
  GemmArgs g4{};
  g4.Bt[0] = S1; g4.C[0] = d_out; g4.bias[0] = nullptr; g4.mode[0] = 2;
  gemm_kernel<<<ggrid1, blk512, 0, stream>>>(B5, g4, MT_, HID_, HID_);
}

// Round 11
// 1292.863 us; speedup vs baseline: 1.0320x; 1.0320x over previous
//
#include <hip/hip_runtime.h>

typedef unsigned short u16;
typedef unsigned int   u32;
typedef __attribute__((ext_vector_type(4))) float f32x4;
typedef __attribute__((ext_vector_type(2))) float f32x2;
typedef __attribute__((ext_vector_type(8))) short bf16x8;

#define B_   4
#define T_   2048
#define HID_ 2048
#define H_   16
#define MT_  (B_*T_)
#define CT_  32
#define NC_  (T_/CT_)

static constexpr float SCALE_ = 0.08838834764831845f; // DK^-0.5
static constexpr float EPS_   = 1e-5f;

__device__ __forceinline__ float sigmoidf_(float x) { return 1.0f / (1.0f + __expf(-x)); }

__device__ __forceinline__ u16 f2bf(float f) {
  union { float f; u32 u; } c; c.f = f;
  u32 r = c.u + 0x7FFFu + ((c.u >> 16) & 1u);
  return (u16)(r >> 16);
}
__device__ __forceinline__ u32 pack2(float a, float b) {
  return (u32)f2bf(a) | ((u32)f2bf(b) << 16);
}
__device__ __forceinline__ float bf2f(u16 h) {
  union { u32 u; float f; } c; c.u = (u32)h << 16; return c.f;
}
__device__ __forceinline__ float u2f_(u32 u) {
  union { u32 u; float f; } c; c.u = u; return c.f;
}
__device__ __forceinline__ void gload16(const u16* g, u16* l) {
  __builtin_amdgcn_global_load_lds((__attribute__((address_space(1))) void*)g,
                                   (__attribute__((address_space(3))) void*)l, 16, 0, 0);
}

// packed fp32 math (VOP3P, full-rate on gfx90a+/gfx950) — compiler won't auto-emit
__device__ __forceinline__ f32x2 pk_fma(f32x2 a, f32x2 b, f32x2 c) {
  f32x2 d;
  asm("v_pk_fma_f32 %0, %1, %2, %3" : "=v"(d) : "v"(a), "v"(b), "v"(c));
  return d;
}
__device__ __forceinline__ f32x2 pk_mul(f32x2 a, f32x2 b) {
  f32x2 d;
  asm("v_pk_mul_f32 %0, %1, %2" : "=v"(d) : "v"(a), "v"(b));
  return d;
}

// DPP butterfly add within 16-lane rows (levels xor1/2/4/8).
template <int CTRL>
__device__ __forceinline__ float dpp_add(float x) {
  int y = __builtin_amdgcn_update_dpp(0, __builtin_bit_cast(int, x), CTRL, 0xF, 0xF, true);
  return x + __builtin_bit_cast(float, y);
}
__device__ __forceinline__ void red16x2(float& d0, float& d1) {
  d0 = dpp_add<0xB1>(d0);  d1 = dpp_add<0xB1>(d1);   // quad_perm {1,0,3,2} : xor1
  d0 = dpp_add<0x4E>(d0);  d1 = dpp_add<0x4E>(d1);   // quad_perm {2,3,0,1} : xor2
  d0 = dpp_add<0x141>(d0); d1 = dpp_add<0x141>(d1);  // row_half_mirror     : ~xor4
  d0 = dpp_add<0x140>(d0); d1 = dpp_add<0x140>(d1);  // row_mirror          : ~xor8
}

// ---------------- x (f32) -> bf16, elementwise ----------------
__global__ __launch_bounds__(256) void convert_bf16_kernel(const float* __restrict__ in,
                                                           u16* __restrict__ out, int n8) {
  int i = blockIdx.x * 256 + threadIdx.x;
  if (i >= n8) return;
  const f32x4* p = (const f32x4*)in + (size_t)i * 2;
  f32x4 v0 = p[0], v1 = p[1];
  uint4 o;
  o.x = pack2(v0[0], v0[1]);
  o.y = pack2(v0[2], v0[3]);
  o.z = pack2(v1[0], v1[1]);
  o.w = pack2(v1[2], v1[3]);
  *(uint4*)(out + (size_t)i * 8) = o;
}

// ---------------- W [K][N] f32 -> WT [N][K] bf16 (tiled transpose, z<=2) ----------------
struct TransArgs { const float* W[2]; u16* WT[2]; };

__global__ __launch_bounds__(256) void transpose_convert_kernel(TransArgs args, int K, int N) {
  __shared__ float tile[64][65];
  const float* __restrict__ W = args.W[blockIdx.z];
  u16* __restrict__ WT = args.WT[blockIdx.z];
  const int t = threadIdx.x;
  const int bk = blockIdx.y * 64;
  const int bn = blockIdx.x * 64;
#pragma unroll
  for (int p = 0; p < 4; ++p) {
    int kl  = p * 16 + (t >> 4);
    int nl4 = (t & 15);
    f32x4 v = *(const f32x4*)(W + (size_t)(bk + kl) * N + bn + nl4 * 4);
    tile[nl4 * 4 + 0][kl] = v[0];
    tile[nl4 * 4 + 1][kl] = v[1];
    tile[nl4 * 4 + 2][kl] = v[2];
    tile[nl4 * 4 + 3][kl] = v[3];
  }
  __syncthreads();
  const int nl = t >> 2;
  const int ko = (t & 3) * 16;
  u32 w[8];
#pragma unroll
  for (int i = 0; i < 8; ++i)
    w[i] = pack2(tile[nl][ko + 2 * i], tile[nl][ko + 2 * i + 1]);
  uint4* dst = (uint4*)(WT + (size_t)(bn + nl) * K + bk + ko);
  dst[0] = make_uint4(w[0], w[1], w[2], w[3]);
  dst[1] = make_uint4(w[4], w[5], w[6], w[7]);
}

// ---- bf16 MFMA GEMM v2 (round-8 best): 256x256, 8 waves, dbuf + counted vmcnt + swizzle ----
// C[M,N] = A[M,K] * BT[N,K]^T.  out mode: 0 = ->bf16, 1 = sigmoid(x+bias)->bf16, 2 = ->f32
struct GemmArgs {
  const u16*   Bt[2];
  void*        C[2];
  const float* bias[2];
  int          mode[2];
};

__global__ __launch_bounds__(512, 2) void gemm_kernel(const u16* __restrict__ A, GemmArgs args,
                                                      int M, int N, int K) {
  __shared__ u16 Al[2][256 * 64];
  __shared__ u16 Bl[2][256 * 64];
  const int mat = blockIdx.z;
  const u16* __restrict__ Bt = args.Bt[mat];
  void* Cp = args.C[mat];
  const float* bias = args.bias[mat];
  const int mode = args.mode[mat];

  const int tid  = threadIdx.x;
  const int wave = tid >> 6;
  const int lane = tid & 63;
  const int tM = blockIdx.y << 8;
  const int tN = blockIdx.x << 8;
  const int wm = wave >> 2;            // 0..1 -> 128 rows each
  const int wn = wave & 3;             // 0..3 ->  64 cols each

  f32x4 acc[8][4] = {};

  // staging map (linear LDS dest; global source col inverse-swizzled)
  const int srow  = tid >> 3;                       // 0..63
  const int cPhys = (tid & 7) << 3;                 // u16
  const int cSrc  = cPhys ^ ((srow & 7) << 3);      // u16

  auto stageAB = [&](int bf, int kt) {
    const int k0 = kt << 6;                          // u16
#pragma unroll
    for (int p = 0; p < 4; ++p) {
      const int row = p * 64 + srow;
      gload16(A  + (size_t)(tM + row) * K + k0 + cSrc, &Al[bf][row * 64 + cPhys]);
      gload16(Bt + (size_t)(tN + row) * K + k0 + cSrc, &Bl[bf][row * 64 + cPhys]);
    }
  };

  // fragment-read map (swizzled to kill the 16-way 128B-stride conflict)
  const int lr  = lane & 15;
  const int lk  = lane >> 4;                        // 0..3
  const int aRow = wm * 128 + lr;
  const int bRow = wn * 64 + lr;
  const int sw  = (lane & 7) << 3;                  // u16
  const int off0 = (lk << 3) ^ sw;                  // kk=0 phys col (u16)
  const int off1 = (32 + (lk << 3)) ^ sw;           // kk=1 phys col (u16)

  const int nt = K >> 6;                            // 32 K-tiles
  stageAB(0, 0);
  stageAB(1, 1);

  for (int t = 0; t < nt; ++t) {
    const int bf = t & 1;
    // wait ONLY for this buffer's 8 loads; next tile's 8 stay in flight (T4)
    if (t + 1 < nt) asm volatile("s_waitcnt vmcnt(8)" ::: "memory");
    else            asm volatile("s_waitcnt vmcnt(0)" ::: "memory");
    __builtin_amdgcn_s_barrier();

#pragma unroll
    for (int kk = 0; kk < 2; ++kk) {
      const int off = kk ? off1 : off0;
      bf16x8 af[8], bfr[4];
#pragma unroll
      for (int i = 0; i < 8; ++i)
        af[i] = *(const bf16x8*)(&Al[bf][(aRow + (i << 4)) * 64 + off]);
#pragma unroll
      for (int j = 0; j < 4; ++j)
        bfr[j] = *(const bf16x8*)(&Bl[bf][(bRow + (j << 4)) * 64 + off]);
#pragma unroll
      for (int i = 0; i < 8; ++i)
#pragma unroll
        for (int j = 0; j < 4; ++j)
          acc[i][j] = __builtin_amdgcn_mfma_f32_16x16x32_bf16(af[i], bfr[j], acc[i][j], 0, 0, 0);
    }
    // all this wave's ds_reads complete before signaling buffer free (rule 18)
    asm volatile("s_waitcnt lgkmcnt(0)" ::: "memory");
    __builtin_amdgcn_s_barrier();
    if (t + 2 < nt) stageAB(bf, t + 2);
  }

  const int r0 = lk << 2;
  const int c0 = lr;
  if (mode == 2) {
    float* Cf = (float*)Cp;
#pragma unroll
    for (int i = 0; i < 8; ++i) {
      const int gm0 = tM + wm * 128 + (i << 4) + r0;
#pragma unroll
      for (int j2 = 0; j2 < 4; ++j2) {
        const int gn = tN + wn * 64 + (j2 << 4) + c0;
#pragma unroll
        for (int rr = 0; rr < 4; ++rr)
          Cf[(size_t)(gm0 + rr) * N + gn] = acc[i][j2][rr];
      }
    }
  } else {
    u16* Cb = (u16*)Cp;
#pragma unroll
    for (int i = 0; i < 8; ++i) {
      const int gm0 = tM + wm * 128 + (i << 4) + r0;
#pragma unroll
      for (int j2 = 0; j2 < 4; ++j2) {
        const int gn = tN + wn * 64 + (j2 << 4) + c0;
        const float bsv = (bias != nullptr) ? bias[gn] : 0.f;
#pragma unroll
        for (int rr = 0; rr < 4; ++rr) {
          float val = acc[i][j2][rr];
          if (mode == 1) val = sigmoidf_(val + bsv);
          Cb[(size_t)(gm0 + rr) * N + gn] = f2bf(val);
        }
      }
    }
  }
}

// ---------------- beta = sigmoid(x @ Wb + bb) : [MT, 16] ----------------
__global__ __launch_bounds__(256) void beta_kernel(const float* __restrict__ x,
                                                   const float* __restrict__ Wb,
                                                   const float* __restrict__ bb,
                                                   float* __restrict__ beta) {
  __shared__ float red[4][64];
  const int tid  = threadIdx.x;
  const int wave = tid >> 6;
  const int lane = tid & 63;
  const size_t row0 = (size_t)blockIdx.x * 4;

  float p[4][16];
#pragma unroll
  for (int r = 0; r < 4; ++r)
#pragma unroll
    for (int h2 = 0; h2 < 16; ++h2) p[r][h2] = 0.f;

  const int e0 = tid * 8;
  f32x4 xa[4][2];
#pragma unroll
  for (int r = 0; r < 4; ++r) {
    xa[r][0] = *(const f32x4*)(x + (row0 + r) * HID_ + e0);
    xa[r][1] = *(const f32x4*)(x + (row0 + r) * HID_ + e0 + 4);
  }
#pragma unroll
  for (int ee = 0; ee < 8; ++ee) {
    const float* wrow = Wb + (size_t)(e0 + ee) * 16;
    f32x4 wv[4];
    wv[0] = *(const f32x4*)(wrow);
    wv[1] = *(const f32x4*)(wrow + 4);
    wv[2] = *(const f32x4*)(wrow + 8);
    wv[3] = *(const f32x4*)(wrow + 12);
#pragma unroll
    for (int r = 0; r < 4; ++r) {
      float xv = xa[r][ee >> 2][ee & 3];
#pragma unroll
      for (int c4 = 0; c4 < 4; ++c4) {
#pragma unroll
        for (int cc = 0; cc < 4; ++cc)
          p[r][c4 * 4 + cc] = fmaf(xv, wv[c4][cc], p[r][c4 * 4 + cc]);
      }
    }
  }
#pragma unroll
  for (int m = 1; m < 64; m <<= 1)
#pragma unroll
    for (int r = 0; r < 4; ++r)
#pragma unroll
      for (int h2 = 0; h2 < 16; ++h2)
        p[r][h2] += __shfl_xor(p[r][h2], m, 64);

  if (lane == 0) {
#pragma unroll
    for (int r = 0; r < 4; ++r)
#pragma unroll
      for (int h2 = 0; h2 < 16; ++h2)
        red[wave][r * 16 + h2] = p[r][h2];
  }
  __syncthreads();
  if (tid < 64) {
    float sres = red[0][tid] + red[1][tid] + red[2][tid] + red[3][tid];
    int r = tid >> 4, h2 = tid & 15;
    beta[(row0 + r) * H_ + h2] = sigmoidf_(sres + bb[h2]);
  }
}

// ---------------- causal depthwise conv (K=4) + silu (+scale), bf16 in/out ----------------
__global__ __launch_bounds__(256) void conv_silu_kernel(const u16* __restrict__ src,
                                                        u16* __restrict__ dst,
                                                        const float* __restrict__ w,
                                                        const float* __restrict__ bias,
                                                        float scale) {
  const int gid = blockIdx.x * 256 + threadIdx.x;   // one group of 8 channels
  const int g8  = gid & 255;                        // 2048/8
  const int row = gid >> 8;                         // b*T + t
  const int t   = row & (T_ - 1);
  const int c   = g8 * 8;

  float acc[8];
  f32x4 b0 = *(const f32x4*)(bias + c);
  f32x4 b1 = *(const f32x4*)(bias + c + 4);
#pragma unroll
  for (int i = 0; i < 4; ++i) { acc[i] = b0[i]; acc[i + 4] = b1[i]; }
  f32x4 wv[8];
#pragma unroll
  for (int i = 0; i < 8; ++i) wv[i] = *(const f32x4*)(w + (size_t)(c + i) * 4);

#pragma unroll
  for (int j = 0; j < 4; ++j) {
    int tt = t - 3 + j;
    if (tt >= 0) {
      uint4 uv = *(const uint4*)(src + (size_t)(row - 3 + j) * HID_ + c);
      const u32 uw[4] = {uv.x, uv.y, uv.z, uv.w};
#pragma unroll
      for (int i = 0; i < 8; ++i) {
        float xval = bf2f((u16)(uw[i >> 1] >> ((i & 1) * 16)));
        acc[i] = fmaf(wv[i][j], xval, acc[i]);
      }
    }
  }
  u32 out[4];
#pragma unroll
  for (int i = 0; i < 4; ++i) {
    float y0 = acc[2 * i]     * sigmoidf_(acc[2 * i])     * scale;
    float y1 = acc[2 * i + 1] * sigmoidf_(acc[2 * i + 1]) * scale;
    out[i] = pack2(y0, y1);
  }
  *(uint4*)(dst + (size_t)row * HID_ + c) = make_uint4(out[0], out[1], out[2], out[3]);
}

// ---------------- gated delta-rule scan v5: v3 structure + packed-fp32 math ----------
// grid: B*H*8 blocks of 256; block = (b,h,vb): 16 v-rows; 16 lanes per row (8 k-elems each).
__global__ __launch_bounds__(256) void scan_kernel(const u16* __restrict__ q,
                                                   const u16* __restrict__ k,
                                                   u16* __restrict__ vo,
                                                   const u16* __restrict__ a,
                                                   const float* __restrict__ beta) {
  __shared__ u16 Kb[2][CT_ * 128];
  __shared__ u16 Qb[2][CT_ * 128];
  __shared__ u16 Vb[2][CT_ * 16];
  __shared__ u16 Ab[2][CT_ * 16];
  __shared__ float Bb[2][CT_];

  const int bid = blockIdx.x;
  const int vb  = bid & 7;
  const int bh  = bid >> 3;
  const int h   = bh & (H_ - 1);
  const int b   = bh >> 4;
  const int tid = threadIdx.x;
  const int wave = tid >> 6;
  const int lane = tid & 63;
  const int r   = tid >> 4;
  const int j   = tid & 15;
  const int vg0 = vb * 16;
  const int vg  = vg0 + r;

  const size_t rs = HID_;
  const size_t base = ((size_t)b * T_) * rs + h * 128;
  const size_t bbase = (size_t)b * T_ * H_ + h;

  const int stt  = wave * 4 + (lane >> 4);
  const int scol = (lane & 15) * 8;
  const int vtt  = lane >> 1;
  const int vhf  = (lane & 1) * 8;

  auto stage = [&](int buf, int tc) {
#pragma unroll
    for (int p = 0; p < 2; ++p) {
      const int tt = p * 16 + stt;
      gload16(k + base + (size_t)(tc + tt) * rs + scol, &Kb[buf][tt * 128 + scol]);
      gload16(q + base + (size_t)(tc + tt) * rs + scol, &Qb[buf][tt * 128 + scol]);
    }
    if (wave == 0) {
      gload16(vo + base + (size_t)(tc + vtt) * rs + vg0 + vhf, &Vb[buf][vtt * 16 + vhf]);
    } else if (wave == 1) {
      gload16(a + base + (size_t)(tc + vtt) * rs + vg0 + vhf, &Ab[buf][vtt * 16 + vhf]);
    }
    if (tid < CT_) Bb[buf][tid] = beta[(bbase) + (size_t)(tc + tid) * H_];
  };

  // 8 bf16 -> 4x f32x2 (pair i holds elements 2i, 2i+1)
  auto cvt8p = [](uint4 raw, f32x2* d) {
    const u32 uw[4] = {raw.x, raw.y, raw.z, raw.w};
#pragma unroll
    for (int i = 0; i < 4; ++i) {
      f32x2 t;
      t[0] = u2f_(uw[i] << 16);
      t[1] = u2f_(uw[i] & 0xffff0000u);
      d[i] = t;
    }
  };

  f32x2 s2[4] = {{0.f, 0.f}, {0.f, 0.f}, {0.f, 0.f}, {0.f, 0.f}};
  f32x2 ka[4], kb_[4];
  float pS = 0.f;
  u16* op = vo + base + vg;
  int buf = 0;

  stage(0, 0);
  __syncthreads();
  cvt8p(*(const uint4*)&Kb[0][j * 8], ka);   // k_0

  for (int c = 0; c < NC_; ++c) {
    const int tc = c * CT_;
    if (c + 1 < NC_) stage(buf ^ 1, tc + CT_);
    uint4 kgn = make_uint4(0, 0, 0, 0);
    if (c + 1 < NC_) kgn = *(const uint4*)(k + base + (size_t)(tc + CT_) * rs + j * 8);

    auto step = [&](int tt, f32x2 (&kc)[4], f32x2 (&kn)[4]) {
      if (tt + 1 < CT_) cvt8p(*(const uint4*)&Kb[buf][(tt + 1) * 128 + j * 8], kn);
      else              cvt8p(kgn, kn);
      f32x2 qc[4];
      cvt8p(*(const uint4*)&Qb[buf][tt * 128 + j * 8], qc);
      const float av = bf2f(Ab[buf][tt * 16 + r]);
      const float vv = bf2f(Vb[buf][tt * 16 + r]);
      const float bt = Bb[buf][tt];

      const float uu = bt * (vv - pS);
      f32x2 uu2; uu2[0] = uu; uu2[1] = uu;
      f32x2 av2; av2[0] = av; av2[1] = av;
#pragma unroll
      for (int i = 0; i < 4; ++i)
        s2[i] = pk_fma(av2, s2[i], pk_mul(uu2, kc[i]));

      // o_t = S_t.q_t ; pS_{t+1} = S_t.k_{t+1} — packed chains
      f32x2 d0p = {0.f, 0.f}, d1p = {0.f, 0.f};
#pragma unroll
      for (int i = 0; i < 4; ++i) {
        d0p = pk_fma(s2[i], qc[i], d0p);
        d1p = pk_fma(s2[i], kn[i], d1p);
      }
      float d0 = d0p[0] + d0p[1], d1 = d1p[0] + d1p[1];
      red16x2(d0, d1);
      if (j == 0) *op = f2bf(d0);
      op += rs;
      pS = d1;
    };

    for (int tt = 0; tt < CT_; tt += 2) {
      step(tt,     ka,  kb_);
      step(tt + 1, kb_, ka);
    }
    __syncthreads();
    buf ^= 1;
  }
}

// ---------------- LayerNorm(DV) * gate -> bf16 ----------------
__global__ __launch_bounds__(256) void ln_gate_kernel(const u16* __restrict__ o,
                                                      const u16* __restrict__ g,
                                                      const float* __restrict__ lnw,
                                                      const float* __restrict__ lnb,
                                                      u16* __restrict__ out) {
  const int wid  = blockIdx.x * 4 + (threadIdx.x >> 6);  // row in [0, MT*H)
  const int lane = threadIdx.x & 63;
  const size_t off = (size_t)wid * 128 + lane * 2;
  u32 oraw = *(const u32*)(o + off);
  float x0 = bf2f((u16)(oraw & 0xffff));
  float x1 = bf2f((u16)(oraw >> 16));
  float sum = x0 + x1;
  float sq  = x0 * x0 + x1 * x1;
#pragma unroll
  for (int m = 1; m < 64; m <<= 1) {
    sum += __shfl_xor(sum, m);
    sq  += __shfl_xor(sq, m);
  }
  float mu  = sum * (1.f / 128.f);
  float var = sq * (1.f / 128.f) - mu * mu;
  float rstd = rsqrtf(var + EPS_);
  int d = lane * 2;
  u32 graw = *(const u32*)(g + off);
  float g0 = bf2f((u16)(graw & 0xffff));
  float g1 = bf2f((u16)(graw >> 16));
  float y0 = ((x0 - mu) * rstd * lnw[d]     + lnb[d])     * g0;
  float y1 = ((x1 - mu) * rstd * lnw[d + 1] + lnb[d + 1]) * g1;
  *(u32*)(out + off) = pack2(y0, y1);
}

// ---------------- host ----------------
extern "C" void kernel_launch(void* const* d_in, const int* in_sizes, int n_in,
                              void* d_out, int out_size, void* d_ws, size_t ws_size,
                              hipStream_t stream) {
  const float* x   = (const float*)d_in[0];
  const float* Wq  = (const float*)d_in[1];
  const float* Wk  = (const float*)d_in[2];
  const float* Wv  = (const float*)d_in[3];
  const float* Wa  = (const float*)d_in[4];
  const float* ba  = (const float*)d_in[5];
  const float* Wb  = (const float*)d_in[6];
  const float* bb  = (const float*)d_in[7];
  const float* Wg  = (const float*)d_in[8];
  const float* Wo  = (const float*)d_in[9];
  const float* qcw = (const float*)d_in[10];
  const float* qcb = (const float*)d_in[11];
  const float* kcw = (const float*)d_in[12];
  const float* kcb = (const float*)d_in[13];
  const float* vcw = (const float*)d_in[14];
  const float* vcb = (const float*)d_in[15];
  const float* lnw = (const float*)d_in[16];
  const float* lnb = (const float*)d_in[17];

  char* ws = (char*)d_ws;
  size_t off = 0;
  auto alloc = [&](size_t bytes) -> char* {
    char* p = ws + off;
    off += (bytes + 255) & ~(size_t)255;
    return p;
  };

  const size_t wtb  = (size_t)HID_ * HID_ * 2;  // 8.39 MB
  const size_t actb = (size_t)MT_ * HID_ * 2;   // 33.55 MB
  u16* S0 = (u16*)alloc(wtb);
  u16* S1 = (u16*)alloc(wtb);
  u16* B1 = (u16*)alloc(actb);
  u16* B2 = (u16*)alloc(actb);
  u16* B3 = (u16*)alloc(actb);
  u16* B4 = (u16*)alloc(actb);
  u16* B5 = (u16*)alloc(actb);
  float* bet = (float*)alloc((size_t)MT_ * H_ * 4);
  // total = 185.1 MB — verified fitting (round 3+)

  if (off > ws_size) return;  // clean-fail guard

  dim3 blk(256);
  dim3 blk512(512);
  dim3 tgrid(32, 32, 2);
  dim3 ggrid(HID_ / 256, MT_ / 256, 2);
  dim3 ggrid1(HID_ / 256, MT_ / 256, 1);
  dim3 vgrid(MT_ * HID_ / 8 / 256);

  // 0. x -> bf16 into B5 (B5 free until conv-q)
  convert_bf16_kernel<<<vgrid, blk, 0, stream>>>(x, B5, MT_ * HID_ / 8);

  // 1. transpose Wq -> S0, Wk -> S1
  TransArgs t1; t1.W[0] = Wq; t1.WT[0] = S0; t1.W[1] = Wk; t1.WT[1] = S1;
  transpose_convert_kernel<<<tgrid, blk, 0, stream>>>(t1, HID_, HID_);

  // 2. GEMM (A = xb): qpre -> B1, kpre -> B2
  GemmArgs g1{};
  g1.Bt[0] = S0; g1.C[0] = B1; g1.bias[0] = nullptr; g1.mode[0] = 0;
  g1.Bt[1] = S1; g1.C[1] = B2; g1.bias[1] = nullptr; g1.mode[1] = 0;
  gemm_kernel<<<ggrid, blk512, 0, stream>>>(B5, g1, MT_, HID_, HID_);

  // 3. transpose Wv -> S0, Wa -> S1
  TransArgs t2; t2.W[0] = Wv; t2.WT[0] = S0; t2.W[1] = Wa; t2.WT[1] = S1;
  transpose_convert_kernel<<<tgrid, blk, 0, stream>>>(t2, HID_, HID_);

  // 4. GEMM (A = xb): vpre -> B3, a-gate (sigmoid+ba) -> B4
  GemmArgs g2{};
  g2.Bt[0] = S0; g2.C[0] = B3; g2.bias[0] = nullptr; g2.mode[0] = 0;
  g2.Bt[1] = S1; g2.C[1] = B4; g2.bias[1] = ba;      g2.mode[1] = 1;
  gemm_kernel<<<ggrid, blk512, 0, stream>>>(B5, g2, MT_, HID_, HID_);

  // 5. beta (reads f32 x directly)
  beta_kernel<<<dim3(MT_ / 4), blk, 0, stream>>>(x, Wb, bb, bet);

  // 6. convs (xb in B5 is dead now; rotation is stream-serialized)
  conv_silu_kernel<<<vgrid, blk, 0, stream>>>(B1, B5, qcw, qcb, 1.0f);    // qc -> B5
  conv_silu_kernel<<<vgrid, blk, 0, stream>>>(B2, B1, kcw, kcb, SCALE_);  // kc -> B1
  conv_silu_kernel<<<vgrid, blk, 0, stream>>>(B3, B2, vcw, vcb, 1.0f);    // vc -> B2

  // 7. scan v5 (256 threads/block): q=B5, k=B1, v/o in-place = B2, a=B4
  scan_kernel<<<dim3(B_ * H_ * 8), blk, 0, stream>>>(B5, B1, B2, B4, bet);

  // 8. transpose Wg -> S0, Wo -> S1
  TransArgs t3; t3.W[0] = Wg; t3.WT[0] = S0; t3.W[1] = Wo; t3.WT[1] = S1;
  transpose_convert_kernel<<<tgrid, blk, 0, stream>>>(t3, HID_, HID_);

  // 8.5. re-convert x -> bf16 into B1 (kc dead after scan)
  convert_bf16_kernel<<<vgrid, blk, 0, stream>>>(x, B1, MT_ * HID_ / 8);

  // 9. GEMM (A = xb2 in B1): g-gate (sigmoid) -> B3 (vpre dead)
  GemmArgs g3{};
  g3.Bt[0] = S0; g3.C[0] = B3; g3.bias[0] = nullptr; g3.mode[0] = 1;
  gemm_kernel<<<ggrid1, blk512, 0, stream>>>(B1, g3, MT_, HID_, HID_);

  // 10. LN * gate: o=B2, g=B3 -> ob=B5 (qc dead)
  ln_gate_kernel<<<dim3(MT_ * H_ / 4), blk, 0, stream>>>(B2, B3, lnw, lnb, B5);

  // 11. final GEMM (A = ob in B5): -> d_out f32
  GemmArgs g4{};
  g4.Bt[0] = S1; g4.C[0] = d_out; g4.bias[0] = nullptr; g4.mode[0] = 2;
  gemm_kernel<<<ggrid1, blk512, 0, stream>>>(B5, g4, MT_, HID_, HID_);
}

// Round 12
// 1258.907 us; speedup vs baseline: 1.0598x; 1.0270x over previous
//
#include <hip/hip_runtime.h>

typedef unsigned short u16;
typedef unsigned int   u32;
typedef __attribute__((ext_vector_type(4))) float f32x4;
typedef __attribute__((ext_vector_type(2))) float f32x2;
typedef __attribute__((ext_vector_type(8))) short bf16x8;

#define B_   4
#define T_   2048
#define HID_ 2048
#define H_   16
#define MT_  (B_*T_)
#define CT_  32
#define NC_  (T_/CT_)

static constexpr float SCALE_ = 0.08838834764831845f; // DK^-0.5
static constexpr float EPS_   = 1e-5f;

__device__ __forceinline__ float sigmoidf_(float x) { return 1.0f / (1.0f + __expf(-x)); }

__device__ __forceinline__ u16 f2bf(float f) {
  union { float f; u32 u; } c; c.f = f;
  u32 r = c.u + 0x7FFFu + ((c.u >> 16) & 1u);
  return (u16)(r >> 16);
}
__device__ __forceinline__ u32 pack2(float a, float b) {
  return (u32)f2bf(a) | ((u32)f2bf(b) << 16);
}
__device__ __forceinline__ float bf2f(u16 h) {
  union { u32 u; float f; } c; c.u = (u32)h << 16; return c.f;
}
__device__ __forceinline__ float u2f_(u32 u) {
  union { u32 u; float f; } c; c.u = u; return c.f;
}
__device__ __forceinline__ void gload16(const u16* g, u16* l) {
  __builtin_amdgcn_global_load_lds((__attribute__((address_space(1))) void*)g,
                                   (__attribute__((address_space(3))) void*)l, 16, 0, 0);
}

// packed fp32 math (VOP3P, full-rate on gfx950)
__device__ __forceinline__ f32x2 pk_fma(f32x2 a, f32x2 b, f32x2 c) {
  f32x2 d;
  asm("v_pk_fma_f32 %0, %1, %2, %3" : "=v"(d) : "v"(a), "v"(b), "v"(c));
  return d;
}
__device__ __forceinline__ f32x2 pk_mul(f32x2 a, f32x2 b) {
  f32x2 d;
  asm("v_pk_mul_f32 %0, %1, %2" : "=v"(d) : "v"(a), "v"(b));
  return d;
}

// DPP butterfly add within 16-lane rows (levels xor1/2/4/8).
template <int CTRL>
__device__ __forceinline__ float dpp_add(float x) {
  int y = __builtin_amdgcn_update_dpp(0, __builtin_bit_cast(int, x), CTRL, 0xF, 0xF, true);
  return x + __builtin_bit_cast(float, y);
}
__device__ __forceinline__ void red16x2(float& d0, float& d1) {
  d0 = dpp_add<0xB1>(d0);  d1 = dpp_add<0xB1>(d1);   // quad_perm {1,0,3,2} : xor1
  d0 = dpp_add<0x4E>(d0);  d1 = dpp_add<0x4E>(d1);   // quad_perm {2,3,0,1} : xor2
  d0 = dpp_add<0x141>(d0); d1 = dpp_add<0x141>(d1);  // row_half_mirror     : ~xor4
  d0 = dpp_add<0x140>(d0); d1 = dpp_add<0x140>(d1);  // row_mirror          : ~xor8
}

// ---------------- x (f32) -> bf16, elementwise ----------------
__global__ __launch_bounds__(256) void convert_bf16_kernel(const float* __restrict__ in,
                                                           u16* __restrict__ out, int n8) {
  int i = blockIdx.x * 256 + threadIdx.x;
  if (i >= n8) return;
  const f32x4* p = (const f32x4*)in + (size_t)i * 2;
  f32x4 v0 = p[0], v1 = p[1];
  uint4 o;
  o.x = pack2(v0[0], v0[1]);
  o.y = pack2(v0[2], v0[3]);
  o.z = pack2(v1[0], v1[1]);
  o.w = pack2(v1[2], v1[3]);
  *(uint4*)(out + (size_t)i * 8) = o;
}

// ---------------- W [K][N] f32 -> WT [N][K] bf16 (tiled transpose, z<=2) ----------------
struct TransArgs { const float* W[2]; u16* WT[2]; };

__global__ __launch_bounds__(256) void transpose_convert_kernel(TransArgs args, int K, int N) {
  __shared__ float tile[64][65];
  const float* __restrict__ W = args.W[blockIdx.z];
  u16* __restrict__ WT = args.WT[blockIdx.z];
  const int t = threadIdx.x;
  const int bk = blockIdx.y * 64;
  const int bn = blockIdx.x * 64;
#pragma unroll
  for (int p = 0; p < 4; ++p) {
    int kl  = p * 16 + (t >> 4);
    int nl4 = (t & 15);
    f32x4 v = *(const f32x4*)(W + (size_t)(bk + kl) * N + bn + nl4 * 4);
    tile[nl4 * 4 + 0][kl] = v[0];
    tile[nl4 * 4 + 1][kl] = v[1];
    tile[nl4 * 4 + 2][kl] = v[2];
    tile[nl4 * 4 + 3][kl] = v[3];
  }
  __syncthreads();
  const int nl = t >> 2;
  const int ko = (t & 3) * 16;
  u32 w[8];
#pragma unroll
  for (int i = 0; i < 8; ++i)
    w[i] = pack2(tile[nl][ko + 2 * i], tile[nl][ko + 2 * i + 1]);
  uint4* dst = (uint4*)(WT + (size_t)(bn + nl) * K + bk + ko);
  dst[0] = make_uint4(w[0], w[1], w[2], w[3]);
  dst[1] = make_uint4(w[4], w[5], w[6], w[7]);
}

// ---- bf16 MFMA GEMM v2 (round-8 best, frozen): 256x256, 8 waves, dbuf + counted vmcnt + swizzle ----
struct GemmArgs {
  const u16*   Bt[2];
  void*        C[2];
  const float* bias[2];
  int          mode[2];
};

__global__ __launch_bounds__(512, 2) void gemm_kernel(const u16* __restrict__ A, GemmArgs args,
                                                      int M, int N, int K) {
  __shared__ u16 Al[2][256 * 64];
  __shared__ u16 Bl[2][256 * 64];
  const int mat = blockIdx.z;
  const u16* __restrict__ Bt = args.Bt[mat];
  void* Cp = args.C[mat];
  const float* bias = args.bias[mat];
  const int mode = args.mode[mat];

  const int tid  = threadIdx.x;
  const int wave = tid >> 6;
  const int lane = tid & 63;
  const int tM = blockIdx.y << 8;
  const int tN = blockIdx.x << 8;
  const int wm = wave >> 2;            // 0..1 -> 128 rows each
  const int wn = wave & 3;             // 0..3 ->  64 cols each

  f32x4 acc[8][4] = {};

  const int srow  = tid >> 3;                       // 0..63
  const int cPhys = (tid & 7) << 3;                 // u16
  const int cSrc  = cPhys ^ ((srow & 7) << 3);      // u16

  auto stageAB = [&](int bf, int kt) {
    const int k0 = kt << 6;                          // u16
#pragma unroll
    for (int p = 0; p < 4; ++p) {
      const int row = p * 64 + srow;
      gload16(A  + (size_t)(tM + row) * K + k0 + cSrc, &Al[bf][row * 64 + cPhys]);
      gload16(Bt + (size_t)(tN + row) * K + k0 + cSrc, &Bl[bf][row * 64 + cPhys]);
    }
  };

  const int lr  = lane & 15;
  const int lk  = lane >> 4;                        // 0..3
  const int aRow = wm * 128 + lr;
  const int bRow = wn * 64 + lr;
  const int sw  = (lane & 7) << 3;                  // u16
  const int off0 = (lk << 3) ^ sw;                  // kk=0 phys col (u16)
  const int off1 = (32 + (lk << 3)) ^ sw;           // kk=1 phys col (u16)

  const int nt = K >> 6;                            // 32 K-tiles
  stageAB(0, 0);
  stageAB(1, 1);

  for (int t = 0; t < nt; ++t) {
    const int bf = t & 1;
    if (t + 1 < nt) asm volatile("s_waitcnt vmcnt(8)" ::: "memory");
    else            asm volatile("s_waitcnt vmcnt(0)" ::: "memory");
    __builtin_amdgcn_s_barrier();

#pragma unroll
    for (int kk = 0; kk < 2; ++kk) {
      const int off = kk ? off1 : off0;
      bf16x8 af[8], bfr[4];
#pragma unroll
      for (int i = 0; i < 8; ++i)
        af[i] = *(const bf16x8*)(&Al[bf][(aRow + (i << 4)) * 64 + off]);
#pragma unroll
      for (int j = 0; j < 4; ++j)
        bfr[j] = *(const bf16x8*)(&Bl[bf][(bRow + (j << 4)) * 64 + off]);
#pragma unroll
      for (int i = 0; i < 8; ++i)
#pragma unroll
        for (int j = 0; j < 4; ++j)
          acc[i][j] = __builtin_amdgcn_mfma_f32_16x16x32_bf16(af[i], bfr[j], acc[i][j], 0, 0, 0);
    }
    asm volatile("s_waitcnt lgkmcnt(0)" ::: "memory");
    __builtin_amdgcn_s_barrier();
    if (t + 2 < nt) stageAB(bf, t + 2);
  }

  const int r0 = lk << 2;
  const int c0 = lr;
  if (mode == 2) {
    float* Cf = (float*)Cp;
#pragma unroll
    for (int i = 0; i < 8; ++i) {
      const int gm0 = tM + wm * 128 + (i << 4) + r0;
#pragma unroll
      for (int j2 = 0; j2 < 4; ++j2) {
        const int gn = tN + wn * 64 + (j2 << 4) + c0;
#pragma unroll
        for (int rr = 0; rr < 4; ++rr)
          Cf[(size_t)(gm0 + rr) * N + gn] = acc[i][j2][rr];
      }
    }
  } else {
    u16* Cb = (u16*)Cp;
#pragma unroll
    for (int i = 0; i < 8; ++i) {
      const int gm0 = tM + wm * 128 + (i << 4) + r0;
#pragma unroll
      for (int j2 = 0; j2 < 4; ++j2) {
        const int gn = tN + wn * 64 + (j2 << 4) + c0;
        const float bsv = (bias != nullptr) ? bias[gn] : 0.f;
#pragma unroll
        for (int rr = 0; rr < 4; ++rr) {
          float val = acc[i][j2][rr];
          if (mode == 1) val = sigmoidf_(val + bsv);
          Cb[(size_t)(gm0 + rr) * N + gn] = f2bf(val);
        }
      }
    }
  }
}

// ---------------- beta = sigmoid(x @ Wb + bb) : [MT, 16] ----------------
__global__ __launch_bounds__(256) void beta_kernel(const float* __restrict__ x,
                                                   const float* __restrict__ Wb,
                                                   const float* __restrict__ bb,
                                                   float* __restrict__ beta) {
  __shared__ float red[4][64];
  const int tid  = threadIdx.x;
  const int wave = tid >> 6;
  const int lane = tid & 63;
  const size_t row0 = (size_t)blockIdx.x * 4;

  float p[4][16];
#pragma unroll
  for (int r = 0; r < 4; ++r)
#pragma unroll
    for (int h2 = 0; h2 < 16; ++h2) p[r][h2] = 0.f;

  const int e0 = tid * 8;
  f32x4 xa[4][2];
#pragma unroll
  for (int r = 0; r < 4; ++r) {
    xa[r][0] = *(const f32x4*)(x + (row0 + r) * HID_ + e0);
    xa[r][1] = *(const f32x4*)(x + (row0 + r) * HID_ + e0 + 4);
  }
#pragma unroll
  for (int ee = 0; ee < 8; ++ee) {
    const float* wrow = Wb + (size_t)(e0 + ee) * 16;
    f32x4 wv[4];
    wv[0] = *(const f32x4*)(wrow);
    wv[1] = *(const f32x4*)(wrow + 4);
    wv[2] = *(const f32x4*)(wrow + 8);
    wv[3] = *(const f32x4*)(wrow + 12);
#pragma unroll
    for (int r = 0; r < 4; ++r) {
      float xv = xa[r][ee >> 2][ee & 3];
#pragma unroll
      for (int c4 = 0; c4 < 4; ++c4) {
#pragma unroll
        for (int cc = 0; cc < 4; ++cc)
          p[r][c4 * 4 + cc] = fmaf(xv, wv[c4][cc], p[r][c4 * 4 + cc]);
      }
    }
  }
#pragma unroll
  for (int m = 1; m < 64; m <<= 1)
#pragma unroll
    for (int r = 0; r < 4; ++r)
#pragma unroll
      for (int h2 = 0; h2 < 16; ++h2)
        p[r][h2] += __shfl_xor(p[r][h2], m, 64);

  if (lane == 0) {
#pragma unroll
    for (int r = 0; r < 4; ++r)
#pragma unroll
      for (int h2 = 0; h2 < 16; ++h2)
        red[wave][r * 16 + h2] = p[r][h2];
  }
  __syncthreads();
  if (tid < 64) {
    float sres = red[0][tid] + red[1][tid] + red[2][tid] + red[3][tid];
    int r = tid >> 4, h2 = tid & 15;
    beta[(row0 + r) * H_ + h2] = sigmoidf_(sres + bb[h2]);
  }
}

// ---------------- causal depthwise conv (K=4) + silu (+scale), bf16 in/out ----------------
__global__ __launch_bounds__(256) void conv_silu_kernel(const u16* __restrict__ src,
                                                        u16* __restrict__ dst,
                                                        const float* __restrict__ w,
                                                        const float* __restrict__ bias,
                                                        float scale) {
  const int gid = blockIdx.x * 256 + threadIdx.x;   // one group of 8 channels
  const int g8  = gid & 255;                        // 2048/8
  const int row = gid >> 8;                         // b*T + t
  const int t   = row & (T_ - 1);
  const int c   = g8 * 8;

  float acc[8];
  f32x4 b0 = *(const f32x4*)(bias + c);
  f32x4 b1 = *(const f32x4*)(bias + c + 4);
#pragma unroll
  for (int i = 0; i < 4; ++i) { acc[i] = b0[i]; acc[i + 4] = b1[i]; }
  f32x4 wv[8];
#pragma unroll
  for (int i = 0; i < 8; ++i) wv[i] = *(const f32x4*)(w + (size_t)(c + i) * 4);

#pragma unroll
  for (int j = 0; j < 4; ++j) {
    int tt = t - 3 + j;
    if (tt >= 0) {
      uint4 uv = *(const uint4*)(src + (size_t)(row - 3 + j) * HID_ + c);
      const u32 uw[4] = {uv.x, uv.y, uv.z, uv.w};
#pragma unroll
      for (int i = 0; i < 8; ++i) {
        float xval = bf2f((u16)(uw[i >> 1] >> ((i & 1) * 16)));
        acc[i] = fmaf(wv[i][j], xval, acc[i]);
      }
    }
  }
  u32 out[4];
#pragma unroll
  for (int i = 0; i < 4; ++i) {
    float y0 = acc[2 * i]     * sigmoidf_(acc[2 * i])     * scale;
    float y1 = acc[2 * i + 1] * sigmoidf_(acc[2 * i + 1]) * scale;
    out[i] = pack2(y0, y1);
  }
  *(uint4*)(dst + (size_t)row * HID_ + c) = make_uint4(out[0], out[1], out[2], out[3]);
}

// ---------------- gated delta-rule scan v6: pk math + hoisted bases + full unroll ----------
// grid: B*H*8 blocks of 256; block = (b,h,vb): 16 v-rows; 16 lanes per row (8 k-elems each).
__global__ __launch_bounds__(256) void scan_kernel(const u16* __restrict__ q,
                                                   const u16* __restrict__ k,
                                                   u16* __restrict__ vo,
                                                   const u16* __restrict__ a,
                                                   const float* __restrict__ beta) {
  __shared__ u16 Kb[2][CT_ * 128];
  __shared__ u16 Qb[2][CT_ * 128];
  __shared__ u16 Vb[2][CT_ * 16];
  __shared__ u16 Ab[2][CT_ * 16];
  __shared__ float Bb[2][CT_];

  const int bid = blockIdx.x;
  const int vb  = bid & 7;
  const int bh  = bid >> 3;
  const int h   = bh & (H_ - 1);
  const int b   = bh >> 4;
  const int tid = threadIdx.x;
  const int wave = tid >> 6;
  const int lane = tid & 63;
  const int r   = tid >> 4;
  const int j   = tid & 15;
  const int vg0 = vb * 16;
  const int vg  = vg0 + r;

  const size_t rs = HID_;
  const size_t base = ((size_t)b * T_) * rs + h * 128;
  const size_t bbase = (size_t)b * T_ * H_ + h;

  const int stt  = wave * 4 + (lane >> 4);
  const int scol = (lane & 15) * 8;
  const int vtt  = lane >> 1;
  const int vhf  = (lane & 1) * 8;

  auto stage = [&](int buf, int tc) {
#pragma unroll
    for (int p = 0; p < 2; ++p) {
      const int tt = p * 16 + stt;
      gload16(k + base + (size_t)(tc + tt) * rs + scol, &Kb[buf][tt * 128 + scol]);
      gload16(q + base + (size_t)(tc + tt) * rs + scol, &Qb[buf][tt * 128 + scol]);
    }
    if (wave == 0) {
      gload16(vo + base + (size_t)(tc + vtt) * rs + vg0 + vhf, &Vb[buf][vtt * 16 + vhf]);
    } else if (wave == 1) {
      gload16(a + base + (size_t)(tc + vtt) * rs + vg0 + vhf, &Ab[buf][vtt * 16 + vhf]);
    }
    if (tid < CT_) Bb[buf][tid] = beta[(bbase) + (size_t)(tc + tid) * H_];
  };

  // 8 bf16 -> 4x f32x2 (pair i holds elements 2i, 2i+1)
  auto cvt8p = [](uint4 raw, f32x2* d) {
    const u32 uw[4] = {raw.x, raw.y, raw.z, raw.w};
#pragma unroll
    for (int i = 0; i < 4; ++i) {
      f32x2 t;
      t[0] = u2f_(uw[i] << 16);
      t[1] = u2f_(uw[i] & 0xffff0000u);
      d[i] = t;
    }
  };

  f32x2 s2[4] = {{0.f, 0.f}, {0.f, 0.f}, {0.f, 0.f}, {0.f, 0.f}};
  f32x2 ka[4], kb_[4];
  float pS = 0.f;
  u16* op = vo + base + vg;
  int buf = 0;

  stage(0, 0);
  __syncthreads();
  cvt8p(*(const uint4*)&Kb[0][j * 8], ka);   // k_0

  for (int c = 0; c < NC_; ++c) {
    const int tc = c * CT_;
    if (c + 1 < NC_) stage(buf ^ 1, tc + CT_);
    uint4 kgn = make_uint4(0, 0, 0, 0);
    if (c + 1 < NC_) kgn = *(const uint4*)(k + base + (size_t)(tc + CT_) * rs + j * 8);

    // hoisted per-chunk base pointers -> ds_read base + immediate offsets under unroll
    const u16* __restrict__ Kp = &Kb[buf][j * 8];
    const u16* __restrict__ Qp = &Qb[buf][j * 8];
    const u16* __restrict__ Vp = &Vb[buf][r];
    const u16* __restrict__ Ap = &Ab[buf][r];
    const float* __restrict__ Bp = &Bb[buf][0];

#pragma unroll
    for (int tt = 0; tt < CT_; tt += 2) {
      // ---- even step tt: consumes ka, produces kb_ (k[tt+1], always in LDS: tt+1<=31)
      {
        cvt8p(*(const uint4*)(Kp + (tt + 1) * 128), kb_);
        f32x2 qc[4];
        cvt8p(*(const uint4*)(Qp + tt * 128), qc);
        const float av = bf2f(Ap[tt * 16]);
        const float vv = bf2f(Vp[tt * 16]);
        const float bt = Bp[tt];
        const float uu = bt * (vv - pS);
        f32x2 uu2; uu2[0] = uu; uu2[1] = uu;
        f32x2 av2; av2[0] = av; av2[1] = av;
#pragma unroll
        for (int i = 0; i < 4; ++i) s2[i] = pk_fma(av2, s2[i], pk_mul(uu2, ka[i]));
        f32x2 d0p = {0.f, 0.f}, d1p = {0.f, 0.f};
#pragma unroll
        for (int i = 0; i < 4; ++i) { d0p = pk_fma(s2[i], qc[i], d0p); d1p = pk_fma(s2[i], kb_[i], d1p); }
        float d0 = d0p[0] + d0p[1], d1 = d1p[0] + d1p[1];
        red16x2(d0, d1);
        if (j == 0) *op = f2bf(d0);
        op += rs;
        pS = d1;
      }
      // ---- odd step tt+1: consumes kb_, produces ka (k[tt+2]; kgn at chunk end)
      {
        if (tt + 2 < CT_) cvt8p(*(const uint4*)(Kp + (tt + 2) * 128), ka);
        else              cvt8p(kgn, ka);
        f32x2 qc[4];
        cvt8p(*(const uint4*)(Qp + (tt + 1) * 128), qc);
        const float av = bf2f(Ap[(tt + 1) * 16]);
        const float vv = bf2f(Vp[(tt + 1) * 16]);
        const float bt = Bp[tt + 1];
        const float uu = bt * (vv - pS);
        f32x2 uu2; uu2[0] = uu; uu2[1] = uu;
        f32x2 av2; av2[0] = av; av2[1] = av;
#pragma unroll
        for (int i = 0; i < 4; ++i) s2[i] = pk_fma(av2, s2[i], pk_mul(uu2, kb_[i]));
        f32x2 d0p = {0.f, 0.f}, d1p = {0.f, 0.f};
#pragma unroll
        for (int i = 0; i < 4; ++i) { d0p = pk_fma(s2[i], qc[i], d0p); d1p = pk_fma(s2[i], ka[i], d1p); }
        float d0 = d0p[0] + d0p[1], d1 = d1p[0] + d1p[1];
        red16x2(d0, d1);
        if (j == 0) *op = f2bf(d0);
        op += rs;
        pS = d1;
      }
    }
    __syncthreads();
    buf ^= 1;
  }
}

// ---------------- LayerNorm(DV) * gate -> bf16 ----------------
__global__ __launch_bounds__(256) void ln_gate_kernel(const u16* __restrict__ o,
                                                      const u16* __restrict__ g,
                                                      const float* __restrict__ lnw,
                                                      const float* __restrict__ lnb,
                                                      u16* __restrict__ out) {
  const int wid  = blockIdx.x * 4 + (threadIdx.x >> 6);  // row in [0, MT*H)
  const int lane = threadIdx.x & 63;
  const size_t off = (size_t)wid * 128 + lane * 2;
  u32 oraw = *(const u32*)(o + off);
  float x0 = bf2f((u16)(oraw & 0xffff));
  float x1 = bf2f((u16)(oraw >> 16));
  float sum = x0 + x1;
  float sq  = x0 * x0 + x1 * x1;
#pragma unroll
  for (int m = 1; m < 64; m <<= 1) {
    sum += __shfl_xor(sum, m);
    sq  += __shfl_xor(sq, m);
  }
  float mu  = sum * (1.f / 128.f);
  float var = sq * (1.f / 128.f) - mu * mu;
  float rstd = rsqrtf(var + EPS_);
  int d = lane * 2;
  u32 graw = *(const u32*)(g + off);
  float g0 = bf2f((u16)(graw & 0xffff));
  float g1 = bf2f((u16)(graw >> 16));
  float y0 = ((x0 - mu) * rstd * lnw[d]     + lnb[d])     * g0;
  float y1 = ((x1 - mu) * rstd * lnw[d + 1] + lnb[d + 1]) * g1;
  *(u32*)(out + off) = pack2(y0, y1);
}

// ---------------- host ----------------
extern "C" void kernel_launch(void* const* d_in, const int* in_sizes, int n_in,
                              void* d_out, int out_size, void* d_ws, size_t ws_size,
                              hipStream_t stream) {
  const float* x   = (const float*)d_in[0];
  const float* Wq  = (const float*)d_in[1];
  const float* Wk  = (const float*)d_in[2];
  const float* Wv  = (const float*)d_in[3];
  const float* Wa  = (const float*)d_in[4];
  const float* ba  = (const float*)d_in[5];
  const float* Wb  = (const float*)d_in[6];
  const float* bb  = (const float*)d_in[7];
  const float* Wg  = (const float*)d_in[8];
  const float* Wo  = (const float*)d_in[9];
  const float* qcw = (const float*)d_in[10];
  const float* qcb = (const float*)d_in[11];
  const float* kcw = (const float*)d_in[12];
  const float* kcb = (const float*)d_in[13];
  const float* vcw = (const float*)d_in[14];
  const float* vcb = (const float*)d_in[15];
  const float* lnw = (const float*)d_in[16];
  const float* lnb = (const float*)d_in[17];

  char* ws = (char*)d_ws;
  size_t off = 0;
  auto alloc = [&](size_t bytes) -> char* {
    char* p = ws + off;
    off += (bytes + 255) & ~(size_t)255;
    return p;
  };

  const size_t wtb  = (size_t)HID_ * HID_ * 2;  // 8.39 MB
  const size_t actb = (size_t)MT_ * HID_ * 2;   // 33.55 MB
  u16* S0 = (u16*)alloc(wtb);
  u16* S1 = (u16*)alloc(wtb);
  u16* B1 = (u16*)alloc(actb);
  u16* B2 = (u16*)alloc(actb);
  u16* B3 = (u16*)alloc(actb);
  u16* B4 = (u16*)alloc(actb);
  u16* B5 = (u16*)alloc(actb);
  float* bet = (float*)alloc((size_t)MT_ * H_ * 4);
  // total = 185.1 MB — verified fitting (round 3+)

  if (off > ws_size) return;  // clean-fail guard

  // g-gate lives in d_out used as bf16 scratch (fully overwritten by final GEMM).
  u16* Dg = (u16*)d_out;      // 33.55 MB of the 67.1 MB f32 output buffer

  dim3 blk(256);
  dim3 blk512(512);
  dim3 tgrid(32, 32, 2);
  dim3 ggrid(HID_ / 256, MT_ / 256, 2);
  dim3 ggrid1(HID_ / 256, MT_ / 256, 1);
  dim3 vgrid(MT_ * HID_ / 8 / 256);

  // 0. x -> bf16 into B5 (xb; alive through all x-GEMMs now)
  convert_bf16_kernel<<<vgrid, blk, 0, stream>>>(x, B5, MT_ * HID_ / 8);

  // 1. transpose Wq -> S0, Wk -> S1
  TransArgs t1; t1.W[0] = Wq; t1.WT[0] = S0; t1.W[1] = Wk; t1.WT[1] = S1;
  transpose_convert_kernel<<<tgrid, blk, 0, stream>>>(t1, HID_, HID_);

  // 2. GEMM (A = xb): qpre -> B1, kpre -> B2
  GemmArgs g1{};
  g1.Bt[0] = S0; g1.C[0] = B1; g1.bias[0] = nullptr; g1.mode[0] = 0;
  g1.Bt[1] = S1; g1.C[1] = B2; g1.bias[1] = nullptr; g1.mode[1] = 0;
  gemm_kernel<<<ggrid, blk512, 0, stream>>>(B5, g1, MT_, HID_, HID_);

  // 3. transpose Wv -> S0, Wa -> S1
  TransArgs t2; t2.W[0] = Wv; t2.WT[0] = S0; t2.W[1] = Wa; t2.WT[1] = S1;
  transpose_convert_kernel<<<tgrid, blk, 0, stream>>>(t2, HID_, HID_);

  // 4. GEMM (A = xb): vpre -> B3, a-gate (sigmoid+ba) -> B4
  GemmArgs g2{};
  g2.Bt[0] = S0; g2.C[0] = B3; g2.bias[0] = nullptr; g2.mode[0] = 0;
  g2.Bt[1] = S1; g2.C[1] = B4; g2.bias[1] = ba;      g2.mode[1] = 1;
  gemm_kernel<<<ggrid, blk512, 0, stream>>>(B5, g2, MT_, HID_, HID_);

  // 5. transpose Wg -> S0, Wo -> S1
  TransArgs t3; t3.W[0] = Wg; t3.WT[0] = S0; t3.W[1] = Wo; t3.WT[1] = S1;
  transpose_convert_kernel<<<tgrid, blk, 0, stream>>>(t3, HID_, HID_);

  // 6. GEMM (A = xb, last use): g-gate (sigmoid) -> Dg (d_out scratch)
  GemmArgs g3{};
  g3.Bt[0] = S0; g3.C[0] = Dg; g3.bias[0] = nullptr; g3.mode[0] = 1;
  gemm_kernel<<<ggrid1, blk512, 0, stream>>>(B5, g3, MT_, HID_, HID_);

  // 7. beta (reads f32 x directly)
  beta_kernel<<<dim3(MT_ / 4), blk, 0, stream>>>(x, Wb, bb, bet);

  // 8. convs (xb dead; rotation is stream-serialized)
  conv_silu_kernel<<<vgrid, blk, 0, stream>>>(B1, B5, qcw, qcb, 1.0f);    // qc -> B5
  conv_silu_kernel<<<vgrid, blk, 0, stream>>>(B2, B1, kcw, kcb, SCALE_);  // kc -> B1
  conv_silu_kernel<<<vgrid, blk, 0, stream>>>(B3, B2, vcw, vcb, 1.0f);    // vc -> B2

  // 9. scan v6: q=B5, k=B1, v/o in-place = B2, a=B4
  scan_kernel<<<dim3(B_ * H_ * 8), blk, 0, stream>>>(B5, B1, B2, B4, bet);

  // 10. LN * gate: o=B2, g=Dg -> B3 (vpre dead)
  ln_gate_kernel<<<dim3(MT_ * H_ / 4), blk, 0, stream>>>(B2, Dg, lnw, lnb, B3);

  // 11. final GEMM (A = B3): -> d_out f32 (overwrites Dg scratch, now dead)
  GemmArgs g4{};
  g4.Bt[0] = S1; g4.C[0] = d_out; g4.bias[0] = nullptr; g4.mode[0] = 2;
  gemm_kernel<<<ggrid1, blk512, 0, stream>>>(B3, g4, MT_, HID_, HID_);
}

// Round 15
// 1257.201 us; speedup vs baseline: 1.0612x; 1.0014x over previous
//
#include <hip/hip_runtime.h>

typedef unsigned short u16;
typedef unsigned int   u32;
typedef __attribute__((ext_vector_type(4))) float f32x4;
typedef __attribute__((ext_vector_type(2))) float f32x2;
typedef __attribute__((ext_vector_type(8))) short bf16x8;

#define B_   4
#define T_   2048
#define HID_ 2048
#define H_   16
#define MT_  (B_*T_)
#define CT_  32
#define NC_  (T_/CT_)

static constexpr float SCALE_ = 0.08838834764831845f; // DK^-0.5
static constexpr float EPS_   = 1e-5f;

__device__ __forceinline__ float sigmoidf_(float x) { return 1.0f / (1.0f + __expf(-x)); }

__device__ __forceinline__ u16 f2bf(float f) {
  union { float f; u32 u; } c; c.f = f;
  u32 r = c.u + 0x7FFFu + ((c.u >> 16) & 1u);
  return (u16)(r >> 16);
}
__device__ __forceinline__ u32 pack2(float a, float b) {
  return (u32)f2bf(a) | ((u32)f2bf(b) << 16);
}
__device__ __forceinline__ float bf2f(u16 h) {
  union { u32 u; float f; } c; c.u = (u32)h << 16; return c.f;
}
__device__ __forceinline__ float u2f_(u32 u) {
  union { u32 u; float f; } c; c.u = u; return c.f;
}
__device__ __forceinline__ void gload16(const u16* g, u16* l) {
  __builtin_amdgcn_global_load_lds((__attribute__((address_space(1))) void*)g,
                                   (__attribute__((address_space(3))) void*)l, 16, 0, 0);
}

// packed fp32 math (VOP3P, full-rate on gfx950)
__device__ __forceinline__ f32x2 pk_fma(f32x2 a, f32x2 b, f32x2 c) {
  f32x2 d;
  asm("v_pk_fma_f32 %0, %1, %2, %3" : "=v"(d) : "v"(a), "v"(b), "v"(c));
  return d;
}
__device__ __forceinline__ f32x2 pk_mul(f32x2 a, f32x2 b) {
  f32x2 d;
  asm("v_pk_mul_f32 %0, %1, %2" : "=v"(d) : "v"(a), "v"(b));
  return d;
}

// DPP butterfly add within 16-lane rows (levels xor1/2/4/8).
// Uses the update_dpp INTRINSIC (not raw asm): the compiler's hazard recognizer
// inserts the required DPP wait-states — raw-asm DPP (round 13/14) miscomputed.
template <int CTRL>
__device__ __forceinline__ float dpp_add(float x) {
  int y = __builtin_amdgcn_update_dpp(0, __builtin_bit_cast(int, x), CTRL, 0xF, 0xF, true);
  return x + __builtin_bit_cast(float, y);
}
__device__ __forceinline__ void red16x2(float& d0, float& d1) {
  d0 = dpp_add<0xB1>(d0);  d1 = dpp_add<0xB1>(d1);   // quad_perm {1,0,3,2} : xor1
  d0 = dpp_add<0x4E>(d0);  d1 = dpp_add<0x4E>(d1);   // quad_perm {2,3,0,1} : xor2
  d0 = dpp_add<0x141>(d0); d1 = dpp_add<0x141>(d1);  // row_half_mirror     : ~xor4
  d0 = dpp_add<0x140>(d0); d1 = dpp_add<0x140>(d1);  // row_mirror          : ~xor8
}

// ---------------- x (f32) -> bf16, elementwise ----------------
__global__ __launch_bounds__(256) void convert_bf16_kernel(const float* __restrict__ in,
                                                           u16* __restrict__ out, int n8) {
  int i = blockIdx.x * 256 + threadIdx.x;
  if (i >= n8) return;
  const f32x4* p = (const f32x4*)in + (size_t)i * 2;
  f32x4 v0 = p[0], v1 = p[1];
  uint4 o;
  o.x = pack2(v0[0], v0[1]);
  o.y = pack2(v0[2], v0[3]);
  o.z = pack2(v1[0], v1[1]);
  o.w = pack2(v1[2], v1[3]);
  *(uint4*)(out + (size_t)i * 8) = o;
}

// ---------------- W [K][N] f32 -> WT [N][K] bf16 (tiled transpose, z<=2) ----------------
struct TransArgs { const float* W[2]; u16* WT[2]; };

__global__ __launch_bounds__(256) void transpose_convert_kernel(TransArgs args, int K, int N) {
  __shared__ float tile[64][65];
  const float* __restrict__ W = args.W[blockIdx.z];
  u16* __restrict__ WT = args.WT[blockIdx.z];
  const int t = threadIdx.x;
  const int bk = blockIdx.y * 64;
  const int bn = blockIdx.x * 64;
#pragma unroll
  for (int p = 0; p < 4; ++p) {
    int kl  = p * 16 + (t >> 4);
    int nl4 = (t & 15);
    f32x4 v = *(const f32x4*)(W + (size_t)(bk + kl) * N + bn + nl4 * 4);
    tile[nl4 * 4 + 0][kl] = v[0];
    tile[nl4 * 4 + 1][kl] = v[1];
    tile[nl4 * 4 + 2][kl] = v[2];
    tile[nl4 * 4 + 3][kl] = v[3];
  }
  __syncthreads();
  const int nl = t >> 2;
  const int ko = (t & 3) * 16;
  u32 w[8];
#pragma unroll
  for (int i = 0; i < 8; ++i)
    w[i] = pack2(tile[nl][ko + 2 * i], tile[nl][ko + 2 * i + 1]);
  uint4* dst = (uint4*)(WT + (size_t)(bn + nl) * K + bk + ko);
  dst[0] = make_uint4(w[0], w[1], w[2], w[3]);
  dst[1] = make_uint4(w[4], w[5], w[6], w[7]);
}

// ---- bf16 MFMA GEMM v2 (round-8 best, frozen): 256x256, 8 waves, dbuf + counted vmcnt + swizzle ----
struct GemmArgs {
  const u16*   Bt[2];
  void*        C[2];
  const float* bias[2];
  int          mode[2];
};

__global__ __launch_bounds__(512, 2) void gemm_kernel(const u16* __restrict__ A, GemmArgs args,
                                                      int M, int N, int K) {
  __shared__ u16 Al[2][256 * 64];
  __shared__ u16 Bl[2][256 * 64];
  const int mat = blockIdx.z;
  const u16* __restrict__ Bt = args.Bt[mat];
  void* Cp = args.C[mat];
  const float* bias = args.bias[mat];
  const int mode = args.mode[mat];

  const int tid  = threadIdx.x;
  const int wave = tid >> 6;
  const int lane = tid & 63;
  const int tM = blockIdx.y << 8;
  const int tN = blockIdx.x << 8;
  const int wm = wave >> 2;            // 0..1 -> 128 rows each
  const int wn = wave & 3;             // 0..3 ->  64 cols each

  f32x4 acc[8][4] = {};

  const int srow  = tid >> 3;                       // 0..63
  const int cPhys = (tid & 7) << 3;                 // u16
  const int cSrc  = cPhys ^ ((srow & 7) << 3);      // u16

  auto stageAB = [&](int bf, int kt) {
    const int k0 = kt << 6;                          // u16
#pragma unroll
    for (int p = 0; p < 4; ++p) {
      const int row = p * 64 + srow;
      gload16(A  + (size_t)(tM + row) * K + k0 + cSrc, &Al[bf][row * 64 + cPhys]);
      gload16(Bt + (size_t)(tN + row) * K + k0 + cSrc, &Bl[bf][row * 64 + cPhys]);
    }
  };

  const int lr  = lane & 15;
  const int lk  = lane >> 4;                        // 0..3
  const int aRow = wm * 128 + lr;
  const int bRow = wn * 64 + lr;
  const int sw  = (lane & 7) << 3;                  // u16
  const int off0 = (lk << 3) ^ sw;                  // kk=0 phys col (u16)
  const int off1 = (32 + (lk << 3)) ^ sw;           // kk=1 phys col (u16)

  const int nt = K >> 6;                            // 32 K-tiles
  stageAB(0, 0);
  stageAB(1, 1);

  for (int t = 0; t < nt; ++t) {
    const int bf = t & 1;
    if (t + 1 < nt) asm volatile("s_waitcnt vmcnt(8)" ::: "memory");
    else            asm volatile("s_waitcnt vmcnt(0)" ::: "memory");
    __builtin_amdgcn_s_barrier();

#pragma unroll
    for (int kk = 0; kk < 2; ++kk) {
      const int off = kk ? off1 : off0;
      bf16x8 af[8], bfr[4];
#pragma unroll
      for (int i = 0; i < 8; ++i)
        af[i] = *(const bf16x8*)(&Al[bf][(aRow + (i << 4)) * 64 + off]);
#pragma unroll
      for (int j = 0; j < 4; ++j)
        bfr[j] = *(const bf16x8*)(&Bl[bf][(bRow + (j << 4)) * 64 + off]);
#pragma unroll
      for (int i = 0; i < 8; ++i)
#pragma unroll
        for (int j = 0; j < 4; ++j)
          acc[i][j] = __builtin_amdgcn_mfma_f32_16x16x32_bf16(af[i], bfr[j], acc[i][j], 0, 0, 0);
    }
    asm volatile("s_waitcnt lgkmcnt(0)" ::: "memory");
    __builtin_amdgcn_s_barrier();
    if (t + 2 < nt) stageAB(bf, t + 2);
  }

  const int r0 = lk << 2;
  const int c0 = lr;
  if (mode == 2) {
    float* Cf = (float*)Cp;
#pragma unroll
    for (int i = 0; i < 8; ++i) {
      const int gm0 = tM + wm * 128 + (i << 4) + r0;
#pragma unroll
      for (int j2 = 0; j2 < 4; ++j2) {
        const int gn = tN + wn * 64 + (j2 << 4) + c0;
#pragma unroll
        for (int rr = 0; rr < 4; ++rr)
          Cf[(size_t)(gm0 + rr) * N + gn] = acc[i][j2][rr];
      }
    }
  } else {
    u16* Cb = (u16*)Cp;
#pragma unroll
    for (int i = 0; i < 8; ++i) {
      const int gm0 = tM + wm * 128 + (i << 4) + r0;
#pragma unroll
      for (int j2 = 0; j2 < 4; ++j2) {
        const int gn = tN + wn * 64 + (j2 << 4) + c0;
        const float bsv = (bias != nullptr) ? bias[gn] : 0.f;
#pragma unroll
        for (int rr = 0; rr < 4; ++rr) {
          float val = acc[i][j2][rr];
          if (mode == 1) val = sigmoidf_(val + bsv);
          Cb[(size_t)(gm0 + rr) * N + gn] = f2bf(val);
        }
      }
    }
  }
}

// ---------------- beta = sigmoid(x @ Wb + bb) : [MT, 16] ----------------
__global__ __launch_bounds__(256) void beta_kernel(const float* __restrict__ x,
                                                   const float* __restrict__ Wb,
                                                   const float* __restrict__ bb,
                                                   float* __restrict__ beta) {
  __shared__ float red[4][64];
  const int tid  = threadIdx.x;
  const int wave = tid >> 6;
  const int lane = tid & 63;
  const size_t row0 = (size_t)blockIdx.x * 4;

  float p[4][16];
#pragma unroll
  for (int r = 0; r < 4; ++r)
#pragma unroll
    for (int h2 = 0; h2 < 16; ++h2) p[r][h2] = 0.f;

  const int e0 = tid * 8;
  f32x4 xa[4][2];
#pragma unroll
  for (int r = 0; r < 4; ++r) {
    xa[r][0] = *(const f32x4*)(x + (row0 + r) * HID_ + e0);
    xa[r][1] = *(const f32x4*)(x + (row0 + r) * HID_ + e0 + 4);
  }
#pragma unroll
  for (int ee = 0; ee < 8; ++ee) {
    const float* wrow = Wb + (size_t)(e0 + ee) * 16;
    f32x4 wv[4];
    wv[0] = *(const f32x4*)(wrow);
    wv[1] = *(const f32x4*)(wrow + 4);
    wv[2] = *(const f32x4*)(wrow + 8);
    wv[3] = *(const f32x4*)(wrow + 12);
#pragma unroll
    for (int r = 0; r < 4; ++r) {
      float xv = xa[r][ee >> 2][ee & 3];
#pragma unroll
      for (int c4 = 0; c4 < 4; ++c4) {
#pragma unroll
        for (int cc = 0; cc < 4; ++cc)
          p[r][c4 * 4 + cc] = fmaf(xv, wv[c4][cc], p[r][c4 * 4 + cc]);
      }
    }
  }
#pragma unroll
  for (int m = 1; m < 64; m <<= 1)
#pragma unroll
    for (int r = 0; r < 4; ++r)
#pragma unroll
      for (int h2 = 0; h2 < 16; ++h2)
        p[r][h2] += __shfl_xor(p[r][h2], m, 64);

  if (lane == 0) {
#pragma unroll
    for (int r = 0; r < 4; ++r)
#pragma unroll
      for (int h2 = 0; h2 < 16; ++h2)
        red[wave][r * 16 + h2] = p[r][h2];
  }
  __syncthreads();
  if (tid < 64) {
    float sres = red[0][tid] + red[1][tid] + red[2][tid] + red[3][tid];
    int r = tid >> 4, h2 = tid & 15;
    beta[(row0 + r) * H_ + h2] = sigmoidf_(sres + bb[h2]);
  }
}

// ---------------- causal depthwise conv (K=4) + silu (+scale), bf16 in/out ----------------
__global__ __launch_bounds__(256) void conv_silu_kernel(const u16* __restrict__ src,
                                                        u16* __restrict__ dst,
                                                        const float* __restrict__ w,
                                                        const float* __restrict__ bias,
                                                        float scale) {
  const int gid = blockIdx.x * 256 + threadIdx.x;   // one group of 8 channels
  const int g8  = gid & 255;                        // 2048/8
  const int row = gid >> 8;                         // b*T + t
  const int t   = row & (T_ - 1);
  const int c   = g8 * 8;

  float acc[8];
  f32x4 b0 = *(const f32x4*)(bias + c);
  f32x4 b1 = *(const f32x4*)(bias + c + 4);
#pragma unroll
  for (int i = 0; i < 4; ++i) { acc[i] = b0[i]; acc[i + 4] = b1[i]; }
  f32x4 wv[8];
#pragma unroll
  for (int i = 0; i < 8; ++i) wv[i] = *(const f32x4*)(w + (size_t)(c + i) * 4);

#pragma unroll
  for (int j = 0; j < 4; ++j) {
    int tt = t - 3 + j;
    if (tt >= 0) {
      uint4 uv = *(const uint4*)(src + (size_t)(row - 3 + j) * HID_ + c);
      const u32 uw[4] = {uv.x, uv.y, uv.z, uv.w};
#pragma unroll
      for (int i = 0; i < 8; ++i) {
        float xval = bf2f((u16)(uw[i >> 1] >> ((i & 1) * 16)));
        acc[i] = fmaf(wv[i][j], xval, acc[i]);
      }
    }
  }
  u32 out[4];
#pragma unroll
  for (int i = 0; i < 4; ++i) {
    float y0 = acc[2 * i]     * sigmoidf_(acc[2 * i])     * scale;
    float y1 = acc[2 * i + 1] * sigmoidf_(acc[2 * i + 1]) * scale;
    out[i] = pack2(y0, y1);
  }
  *(uint4*)(dst + (size_t)row * HID_ + c) = make_uint4(out[0], out[1], out[2], out[3]);
}

// ---------------- gated delta-rule scan v7 (round-12 verified): pk math + unroll ----------
// grid: B*H*8 blocks of 256; block = (b,h,vb): 16 v-rows; 16 lanes per row (8 k-elems each).
__global__ __launch_bounds__(256) void scan_kernel(const u16* __restrict__ q,
                                                   const u16* __restrict__ k,
                                                   u16* __restrict__ vo,
                                                   const u16* __restrict__ a,
                                                   const float* __restrict__ beta) {
  __shared__ u16 Kb[2][CT_ * 128];
  __shared__ u16 Qb[2][CT_ * 128];
  __shared__ u16 Vb[2][CT_ * 16];
  __shared__ u16 Ab[2][CT_ * 16];
  __shared__ float Bb[2][CT_];

  const int bid = blockIdx.x;
  const int vb  = bid & 7;
  const int bh  = bid >> 3;
  const int h   = bh & (H_ - 1);
  const int b   = bh >> 4;
  const int tid = threadIdx.x;
  const int wave = tid >> 6;
  const int lane = tid & 63;
  const int r   = tid >> 4;
  const int j   = tid & 15;
  const int vg0 = vb * 16;
  const int vg  = vg0 + r;

  const size_t rs = HID_;
  const size_t base = ((size_t)b * T_) * rs + h * 128;
  const size_t bbase = (size_t)b * T_ * H_ + h;

  const int stt  = wave * 4 + (lane >> 4);
  const int scol = (lane & 15) * 8;
  const int vtt  = lane >> 1;
  const int vhf  = (lane & 1) * 8;

  auto stage = [&](int buf, int tc) {
#pragma unroll
    for (int p = 0; p < 2; ++p) {
      const int tt = p * 16 + stt;
      gload16(k + base + (size_t)(tc + tt) * rs + scol, &Kb[buf][tt * 128 + scol]);
      gload16(q + base + (size_t)(tc + tt) * rs + scol, &Qb[buf][tt * 128 + scol]);
    }
    if (wave == 0) {
      gload16(vo + base + (size_t)(tc + vtt) * rs + vg0 + vhf, &Vb[buf][vtt * 16 + vhf]);
    } else if (wave == 1) {
      gload16(a + base + (size_t)(tc + vtt) * rs + vg0 + vhf, &Ab[buf][vtt * 16 + vhf]);
    }
    if (tid < CT_) Bb[buf][tid] = beta[(bbase) + (size_t)(tc + tid) * H_];
  };

  // 8 bf16 -> 4x f32x2 (pair i holds elements 2i, 2i+1)
  auto cvt8p = [](uint4 raw, f32x2* d) {
    const u32 uw[4] = {raw.x, raw.y, raw.z, raw.w};
#pragma unroll
    for (int i = 0; i < 4; ++i) {
      f32x2 t;
      t[0] = u2f_(uw[i] << 16);
      t[1] = u2f_(uw[i] & 0xffff0000u);
      d[i] = t;
    }
  };

  f32x2 s2[4] = {{0.f, 0.f}, {0.f, 0.f}, {0.f, 0.f}, {0.f, 0.f}};
  f32x2 ka[4], kb_[4];
  float pS = 0.f;
  u16* op = vo + base + vg;
  int buf = 0;

  stage(0, 0);
  __syncthreads();
  cvt8p(*(const uint4*)&Kb[0][j * 8], ka);   // k_0

  for (int c = 0; c < NC_; ++c) {
    const int tc = c * CT_;
    if (c + 1 < NC_) stage(buf ^ 1, tc + CT_);
    uint4 kgn = make_uint4(0, 0, 0, 0);
    if (c + 1 < NC_) kgn = *(const uint4*)(k + base + (size_t)(tc + CT_) * rs + j * 8);

    // hoisted per-chunk base pointers -> ds_read base + immediate offsets under unroll
    const u16* __restrict__ Kp = &Kb[buf][j * 8];
    const u16* __restrict__ Qp = &Qb[buf][j * 8];
    const u16* __restrict__ Vp = &Vb[buf][r];
    const u16* __restrict__ Ap = &Ab[buf][r];
    const float* __restrict__ Bp = &Bb[buf][0];

#pragma unroll
    for (int tt = 0; tt < CT_; tt += 2) {
      // ---- even step tt: consumes ka, produces kb_ (k[tt+1], always in LDS)
      {
        cvt8p(*(const uint4*)(Kp + (tt + 1) * 128), kb_);
        f32x2 qc[4];
        cvt8p(*(const uint4*)(Qp + tt * 128), qc);
        const float av = bf2f(Ap[tt * 16]);
        const float vv = bf2f(Vp[tt * 16]);
        const float bt = Bp[tt];
        const float uu = bt * (vv - pS);
        f32x2 uu2; uu2[0] = uu; uu2[1] = uu;
        f32x2 av2; av2[0] = av; av2[1] = av;
#pragma unroll
        for (int i = 0; i < 4; ++i) s2[i] = pk_fma(av2, s2[i], pk_mul(uu2, ka[i]));
        f32x2 d0p = {0.f, 0.f}, d1p = {0.f, 0.f};
#pragma unroll
        for (int i = 0; i < 4; ++i) { d0p = pk_fma(s2[i], qc[i], d0p); d1p = pk_fma(s2[i], kb_[i], d1p); }
        float d0 = d0p[0] + d0p[1], d1 = d1p[0] + d1p[1];
        red16x2(d0, d1);
        if (j == 0) *op = f2bf(d0);
        op += rs;
        pS = d1;
      }
      // ---- odd step tt+1: consumes kb_, produces ka (k[tt+2]; kgn at chunk end)
      {
        if (tt + 2 < CT_) cvt8p(*(const uint4*)(Kp + (tt + 2) * 128), ka);
        else              cvt8p(kgn, ka);
        f32x2 qc[4];
        cvt8p(*(const uint4*)(Qp + (tt + 1) * 128), qc);
        const float av = bf2f(Ap[(tt + 1) * 16]);
        const float vv = bf2f(Vp[(tt + 1) * 16]);
        const float bt = Bp[tt + 1];
        const float uu = bt * (vv - pS);
        f32x2 uu2; uu2[0] = uu; uu2[1] = uu;
        f32x2 av2; av2[0] = av; av2[1] = av;
#pragma unroll
        for (int i = 0; i < 4; ++i) s2[i] = pk_fma(av2, s2[i], pk_mul(uu2, kb_[i]));
        f32x2 d0p = {0.f, 0.f}, d1p = {0.f, 0.f};
#pragma unroll
        for (int i = 0; i < 4; ++i) { d0p = pk_fma(s2[i], qc[i], d0p); d1p = pk_fma(s2[i], ka[i], d1p); }
        float d0 = d0p[0] + d0p[1], d1 = d1p[0] + d1p[1];
        red16x2(d0, d1);
        if (j == 0) *op = f2bf(d0);
        op += rs;
        pS = d1;
      }
    }
    __syncthreads();
    buf ^= 1;
  }
}

// ---------------- LayerNorm(DV) * gate -> bf16 ----------------
__global__ __launch_bounds__(256) void ln_gate_kernel(const u16* __restrict__ o,
                                                      const u16* __restrict__ g,
                                                      const float* __restrict__ lnw,
                                                      const float* __restrict__ lnb,
                                                      u16* __restrict__ out) {
  const int wid  = blockIdx.x * 4 + (threadIdx.x >> 6);  // row in [0, MT*H)
  const int lane = threadIdx.x & 63;
  const size_t off = (size_t)wid * 128 + lane * 2;
  u32 oraw = *(const u32*)(o + off);
  float x0 = bf2f((u16)(oraw & 0xffff));
  float x1 = bf2f((u16)(oraw >> 16));
  float sum = x0 + x1;
  float sq  = x0 * x0 + x1 * x1;
#pragma unroll
  for (int m = 1; m < 64; m <<= 1) {
    sum += __shfl_xor(sum, m);
    sq  += __shfl_xor(sq, m);
  }
  float mu  = sum * (1.f / 128.f);
  float var = sq * (1.f / 128.f) - mu * mu;
  float rstd = rsqrtf(var + EPS_);
  int d = lane * 2;
  u32 graw = *(const u32*)(g + off);
  float g0 = bf2f((u16)(graw & 0xffff));
  float g1 = bf2f((u16)(graw >> 16));
  float y0 = ((x0 - mu) * rstd * lnw[d]     + lnb[d])     * g0;
  float y1 = ((x1 - mu) * rstd * lnw[d + 1] + lnb[d + 1]) * g1;
  *(u32*)(out + off) = pack2(y0, y1);
}

// ---------------- host ----------------
extern "C" void kernel_launch(void* const* d_in, const int* in_sizes, int n_in,
                              void* d_out, int out_size, void* d_ws, size_t ws_size,
                              hipStream_t stream) {
  const float* x   = (const float*)d_in[0];
  const float* Wq  = (const float*)d_in[1];
  const float* Wk  = (const float*)d_in[2];
  const float* Wv  = (const float*)d_in[3];
  const float* Wa  = (const float*)d_in[4];
  const float* ba  = (const float*)d_in[5];
  const float* Wb  = (const float*)d_in[6];
  const float* bb  = (const float*)d_in[7];
  const float* Wg  = (const float*)d_in[8];
  const float* Wo  = (const float*)d_in[9];
  const float* qcw = (const float*)d_in[10];
  const float* qcb = (const float*)d_in[11];
  const float* kcw = (const float*)d_in[12];
  const float* kcb = (const float*)d_in[13];
  const float* vcw = (const float*)d_in[14];
  const float* vcb = (const float*)d_in[15];
  const float* lnw = (const float*)d_in[16];
  const float* lnb = (const float*)d_in[17];

  char* ws = (char*)d_ws;
  size_t off = 0;
  auto alloc = [&](size_t bytes) -> char* {
    char* p = ws + off;
    off += (bytes + 255) & ~(size_t)255;
    return p;
  };

  const size_t wtb  = (size_t)HID_ * HID_ * 2;  // 8.39 MB
  const size_t actb = (size_t)MT_ * HID_ * 2;   // 33.55 MB
  u16* S0 = (u16*)alloc(wtb);
  u16* S1 = (u16*)alloc(wtb);
  u16* B1 = (u16*)alloc(actb);
  u16* B2 = (u16*)alloc(actb);
  u16* B3 = (u16*)alloc(actb);
  u16* B4 = (u16*)alloc(actb);
  u16* B5 = (u16*)alloc(actb);
  float* bet = (float*)alloc((size_t)MT_ * H_ * 4);
  // total = 185.1 MB — verified fitting (round 3+)

  if (off > ws_size) return;  // clean-fail guard

  // g-gate lives in d_out used as bf16 scratch (fully overwritten by final GEMM).
  u16* Dg = (u16*)d_out;      // 33.55 MB of the 67.1 MB f32 output buffer

  dim3 blk(256);
  dim3 blk512(512);
  dim3 tgrid(32, 32, 2);
  dim3 ggrid(HID_ / 256, MT_ / 256, 2);
  dim3 ggrid1(HID_ / 256, MT_ / 256, 1);
  dim3 vgrid(MT_ * HID_ / 8 / 256);

  // 0. x -> bf16 into B5 (xb; alive through all x-GEMMs)
  convert_bf16_kernel<<<vgrid, blk, 0, stream>>>(x, B5, MT_ * HID_ / 8);

  // 1. transpose Wq -> S0, Wk -> S1
  TransArgs t1; t1.W[0] = Wq; t1.WT[0] = S0; t1.W[1] = Wk; t1.WT[1] = S1;
  transpose_convert_kernel<<<tgrid, blk, 0, stream>>>(t1, HID_, HID_);

  // 2. GEMM (A = xb): qpre -> B1, kpre -> B2
  GemmArgs g1{};
  g1.Bt[0] = S0; g1.C[0] = B1; g1.bias[0] = nullptr; g1.mode[0] = 0;
  g1.Bt[1] = S1; g1.C[1] = B2; g1.bias[1] = nullptr; g1.mode[1] = 0;
  gemm_kernel<<<ggrid, blk512, 0, stream>>>(B5, g1, MT_, HID_, HID_);

  // 3. transpose Wv -> S0, Wa -> S1
  TransArgs t2; t2.W[0] = Wv; t2.WT[0] = S0; t2.W[1] = Wa; t2.WT[1] = S1;
  transpose_convert_kernel<<<tgrid, blk, 0, stream>>>(t2, HID_, HID_);

  // 4. GEMM (A = xb): vpre -> B3, a-gate (sigmoid+ba) -> B4
  GemmArgs g2{};
  g2.Bt[0] = S0; g2.C[0] = B3; g2.bias[0] = nullptr; g2.mode[0] = 0;
  g2.Bt[1] = S1; g2.C[1] = B4; g2.bias[1] = ba;      g2.mode[1] = 1;
  gemm_kernel<<<ggrid, blk512, 0, stream>>>(B5, g2, MT_, HID_, HID_);

  // 5. transpose Wg -> S0, Wo -> S1
  TransArgs t3; t3.W[0] = Wg; t3.WT[0] = S0; t3.W[1] = Wo; t3.WT[1] = S1;
  transpose_convert_kernel<<<tgrid, blk, 0, stream>>>(t3, HID_, HID_);

  // 6. GEMM (A = xb, last use): g-gate (sigmoid) -> Dg (d_out scratch)
  GemmArgs g3{};
  g3.Bt[0] = S0; g3.C[0] = Dg; g3.bias[0] = nullptr; g3.mode[0] = 1;
  gemm_kernel<<<ggrid1, blk512, 0, stream>>>(B5, g3, MT_, HID_, HID_);

  // 7. beta (reads f32 x directly)
  beta_kernel<<<dim3(MT_ / 4), blk, 0, stream>>>(x, Wb, bb, bet);

  // 8. convs (xb dead; rotation is stream-serialized)
  conv_silu_kernel<<<vgrid, blk, 0, stream>>>(B1, B5, qcw, qcb, 1.0f);    // qc -> B5
  conv_silu_kernel<<<vgrid, blk, 0, stream>>>(B2, B1, kcw, kcb, SCALE_);  // kc -> B1
  conv_silu_kernel<<<vgrid, blk, 0, stream>>>(B3, B2, vcw, vcb, 1.0f);    // vc -> B2

  // 9. scan v7: q=B5, k=B1, v/o in-place = B2, a=B4
  scan_kernel<<<dim3(B_ * H_ * 8), blk, 0, stream>>>(B5, B1, B2, B4, bet);

  // 10. LN * gate: o=B2, g=Dg -> B3 (vpre dead)
  ln_gate_kernel<<<dim3(MT_ * H_ / 4), blk, 0, stream>>>(B2, Dg, lnw, lnb, B3);

  // 11. final GEMM (A = B3): -> d_out f32 (overwrites Dg scratch, now dead)
  GemmArgs g4{};
  g4.Bt[0] = S1; g4.C[0] = d_out; g4.bias[0] = nullptr; g4.mode[0] = 2;
  gemm_kernel<<<ggrid1, blk512, 0, stream>>>(B3, g4, MT_, HID_, HID_);
}